// Round 1
// baseline (1096.184 us; speedup 1.0000x reference)
//
#include <hip/hip_runtime.h>
#include <math.h>

// ParallelSMLSTMCell decomposed: never materialize C[B,S,D,D].
// B=8 S=512 F=32 D=64, window w=102. All f32.
#define BB 8
#define SS 512
#define FF 32
#define DD 64
#define WVOL 102

__device__ __forceinline__ float wred64(float v) {
#pragma unroll
  for (int m = 1; m < 64; m <<= 1) v += __shfl_xor(v, m, 64);
  return v;
}
__device__ __forceinline__ float wred32(float v) {
#pragma unroll
  for (int m = 1; m < 32; m <<= 1) v += __shfl_xor(v, m, 32);
  return v;
}

// ---------------- K1: rolling-window volatility -> sv[b][s] ----------------
__global__ void k_vol(const float* __restrict__ x, float* __restrict__ sv) {
  int b = blockIdx.x;
  int lane = threadIdx.x;
  __shared__ float sv0[SS];
  __shared__ float s_inv;
  float wsum = 0.f, wsq = 0.f, tot = 0.f;
  for (int s = 0; s < SS; ++s) {
    float m = 0.f;
    if (lane < FF) {
      float xv = x[(b * SS + s) * FF + lane];
      wsum += xv; wsq += xv * xv;
      if (s >= WVOL) {
        float xo = x[(b * SS + s - WVOL) * FF + lane];
        wsum -= xo; wsq -= xo * xo;
      }
      if (s >= WVOL - 1) {
        float var = (wsq - wsum * wsum / (float)WVOL) / (float)(WVOL - 1);
        float sd = sqrtf(fmaxf(var, 0.f));
        m = wred32(sd) * (1.f / FF);
      }
    }
    if (s >= WVOL - 1 && lane == 0) { sv0[s] = m; tot += m; }
  }
  __syncthreads();
  if (lane == 0) {
    float m0 = sv0[WVOL - 1];
    for (int s = 0; s < WVOL - 1; ++s) { sv0[s] = m0; tot += m0; }
    s_inv = 1.f / (tot / (float)SS + 1e-6f);
  }
  __syncthreads();
  float inv = s_inv;
  for (int s = lane; s < SS; s += 64) sv[b * SS + s] = sv0[s] * inv;
}

// ---------------- K2: per-(b,s) LN + projections + gates ----------------
__global__ void k_proj(const float* __restrict__ x, const float* __restrict__ m_prev,
                       const float* __restrict__ ln_in_g, const float* __restrict__ ln_in_b,
                       const float* __restrict__ wq, const float* __restrict__ bq,
                       const float* __restrict__ wk, const float* __restrict__ bk,
                       const float* __restrict__ wv, const float* __restrict__ bv,
                       const float* __restrict__ wi, const float* __restrict__ bi,
                       const float* __restrict__ wf, const float* __restrict__ bf,
                       const float* __restrict__ wo, const float* __restrict__ bo,
                       const float* __restrict__ rd_w1, const float* __restrict__ rd_b1,
                       const float* __restrict__ rd_g, const float* __restrict__ rd_be,
                       const float* __restrict__ rd_w2, const float* __restrict__ rd_b2,
                       float* __restrict__ qo, float* __restrict__ kno, float* __restrict__ vno,
                       float* __restrict__ iko, float* __restrict__ oo,
                       float* __restrict__ knT, float* __restrict__ vnT,
                       float* __restrict__ cg_a, float* __restrict__ fg_a,
                       float* __restrict__ mf_a, float* __restrict__ cks_a,
                       float* __restrict__ qsum_a) {
  int bs = blockIdx.x; int b = bs / SS; int s = bs % SS;
  int lane = threadIdx.x;
  __shared__ float xs[FF];
  if (lane < FF) {
    float xv = x[bs * FF + lane];
    float s1 = wred32(xv);
    float s2 = wred32(xv * xv);
    float mu = s1 * (1.f / FF);
    float var = s2 * (1.f / FF) - mu * mu;
    xs[lane] = (xv - mu) * rsqrtf(var + 1e-5f) * ln_in_g[lane] + ln_in_b[lane];
  }
  __syncthreads();
  int d = lane;
  float aq = bq[d], ak = bk[d], av = bv[d], ao = bo[d], at = rd_b1[d];
#pragma unroll
  for (int f = 0; f < FF; ++f) {
    float xf = xs[f];
    aq = fmaf(xf, wq[d * FF + f], aq);
    ak = fmaf(xf, wk[d * FF + f], ak);
    av = fmaf(xf, wv[d * FF + f], av);
    ao = fmaf(xf, wo[d * FF + f], ao);
    at = fmaf(xf, rd_w1[d * FF + f], at);
  }
  float pit = 0.f, pft = 0.f;
  if (lane < FF) { pit = xs[lane] * wi[lane]; pft = xs[lane] * wf[lane]; }
  pit = wred32(pit); pft = wred32(pft);
  float itv = __shfl(pit, 0, 64) + bi[0];
  float ftv = __shfl(pft, 0, 64) + bf[0];
  // regime head: LN(D) -> gelu(exact) -> 4 logits -> softmax[0]
  float s1 = wred64(at), s2 = wred64(at * at);
  float mu = s1 * (1.f / DD);
  float var = s2 * (1.f / DD) - mu * mu;
  float tn = (at - mu) * rsqrtf(var + 1e-5f) * rd_g[d] + rd_be[d];
  float ge = 0.5f * tn * (1.f + erff(tn * 0.70710678118654752f));
  float l0 = wred64(ge * rd_w2[0 * DD + d]) + rd_b2[0];
  float l1 = wred64(ge * rd_w2[1 * DD + d]) + rd_b2[1];
  float l2 = wred64(ge * rd_w2[2 * DD + d]) + rd_b2[2];
  float l3 = wred64(ge * rd_w2[3 * DD + d]) + rd_b2[3];
  float mx = fmaxf(fmaxf(l0, l1), fmaxf(l2, l3));
  float e0 = expf(l0 - mx), e1 = expf(l1 - mx), e2 = expf(l2 - mx), e3 = expf(l3 - mx);
  float mfv = e0 / (e0 + e1 + e2 + e3);
  // normalize k, v
  float kd = ak * 0.125f;                       // k = (.)/sqrt(D)
  float kk = wred64(kd * kd);
  float knd = kd * (8.f / (sqrtf(kk) + 1e-12f));
  float vv = wred64(av * av);
  float vnd = av * (8.f / (sqrtf(vv) + 1e-6f));
  float ksum = wred64(knd);
  float qsum = wred64(aq);
  // stabilized gates
  float mp = fminf(fmaxf(m_prev[b], -100.f), 100.f);
  float mt = fmaxf(ftv, mp + ftv);
  float ig = expf(fminf(fmaxf(itv - mt, -15.f), 15.f));
  float fg = expf(fminf(fmaxf(ftv + mp - mt, -15.f), 15.f));
  float cg = fminf(ig, 1.f);
  qo[bs * DD + d] = aq;
  kno[bs * DD + d] = knd;
  vno[bs * DD + d] = vnd;
  iko[bs * DD + d] = ig * kd;
  oo[bs * DD + d] = 1.f / (1.f + expf(-ao));
  knT[(b * DD + d) * SS + s] = knd;
  vnT[(b * DD + d) * SS + s] = vnd;
  if (lane == 0) {
    cg_a[bs] = cg; fg_a[bs] = fg; mf_a[bs] = mfv;
    cks_a[bs] = cg * ksum; qsum_a[bs] = qsum;
  }
}

// ---------------- K3a: zc[b,t] = cg_t * vn^T Cp kn ----------------
__global__ void k_zc(const float* __restrict__ kno, const float* __restrict__ vno,
                     const float* __restrict__ Cp, const float* __restrict__ cg_a,
                     float* __restrict__ zc) {
  int bs = blockIdx.x; int b = bs / SS;
  int i = threadIdx.x;
  __shared__ float ks[DD];
  ks[i] = kno[bs * DD + i];
  __syncthreads();
  float acc = 0.f;
  const float* cr = Cp + (b * DD + i) * DD;
#pragma unroll
  for (int j = 0; j < DD; ++j) acc = fmaf(cr[j], ks[j], acc);
  float z = wred64(vno[bs * DD + i] * acc);
  if (i == 0) zc[bs] = cg_a[bs] * z;
}

// ---------------- K3b: per-b sequential prefix scans ----------------
__global__ void k_scan(const float* __restrict__ Cp,
                       const float* __restrict__ ik, const float* __restrict__ vno,
                       const float* __restrict__ fg_a, const float* __restrict__ cks_a,
                       const float* __restrict__ zc,
                       float* __restrict__ nacc, float* __restrict__ racc,
                       float* __restrict__ fcum, float* __restrict__ cpd,
                       float* __restrict__ cpr, float* __restrict__ cpn2) {
  int b = blockIdx.x; int d = threadIdx.x;
  const float* cr = Cp + (b * DD + d) * DD;
  float rs = 0.f, r2 = 0.f;
#pragma unroll
  for (int j = 0; j < DD; ++j) { float c = cr[j]; rs += c; r2 = fmaf(c, c, r2); }
  cpr[b * DD + d] = rs;
  float tot2 = wred64(r2);
  if (d == 0) cpn2[b] = tot2;
  float na = 0.f, ra = 0.f, fc = 1.f, cd = 0.f;
  for (int s = 0; s < SS; ++s) {
    int bs = b * SS + s;
    fc *= fg_a[bs];
    cd += zc[bs];
    na += ik[bs * DD + d];
    ra = fmaf(cks_a[bs], vno[bs * DD + d], ra);
    nacc[bs * DD + d] = na;
    racc[bs * DD + d] = ra;
    if (d == 0) { fcum[bs] = fc; cpd[bs] = cd; }
  }
}

// ---------------- K4: O(S^2) linear-attn p2 + Gram rho ----------------
__global__ void k_main(const float* __restrict__ qo, const float* __restrict__ kno,
                       const float* __restrict__ vno,
                       const float* __restrict__ knT, const float* __restrict__ vnT,
                       const float* __restrict__ cg_a,
                       float* __restrict__ p2, float* __restrict__ rho) {
  int bs = blockIdx.x; int b = bs / SS; int s = bs % SS;
  int lane = threadIdx.x;
  __shared__ float w[64];
  const float* qrow = qo + bs * DD;   // wave-uniform -> s_load
  const float* krow = kno + bs * DD;
  const float* vrow = vno + bs * DD;
  float pacc = 0.f, rp = 0.f;
  int ntile = s / 64 + 1;
  for (int T = 0; T < ntile * 64; T += 64) {
    int t = T + lane;
    float A = 0.f, KK = 0.f, VV = 0.f;
#pragma unroll 8
    for (int j = 0; j < DD; ++j) {
      float kt = knT[(b * DD + j) * SS + t];   // coalesced over lanes
      float vt = vnT[(b * DD + j) * SS + t];
      A = fmaf(kt, qrow[j], A);
      KK = fmaf(kt, krow[j], KK);
      VV = fmaf(vt, vrow[j], VV);
    }
    float cgt = cg_a[b * SS + t];
    w[lane] = (t <= s) ? cgt * A : 0.f;
    float wr = (t < s) ? 2.f : (t == s ? 1.f : 0.f);
    rp = fmaf(wr * cgt, KK * VV, rp);
    __syncthreads();
    int tmax = min(63, s - T);
    for (int tl = 0; tl <= tmax; ++tl) {
      float wt = w[tl];
      float vnv = vno[(b * SS + T + tl) * DD + lane];  // coalesced
      pacc = fmaf(wt, vnv, pacc);
    }
    __syncthreads();
  }
  p2[bs * DD + lane] = pacc;
  float rr = wred64(rp);
  if (lane == 0) rho[bs] = cg_a[bs] * rr;
}

// ---------------- K4b: sn2 = cumsum_s(rho) ----------------
__global__ void k_sn2(const float* __restrict__ rho, float* __restrict__ sn2) {
  int b = threadIdx.x;
  if (b < BB) {
    float acc = 0.f;
    for (int s = 0; s < SS; ++s) { acc += rho[b * SS + s]; sn2[b * SS + s] = acc; }
  }
}

// ---------------- K5: SSM scan, one wave per (b, row i) ----------------
__global__ void k_ssm(const float* __restrict__ fcum, const float* __restrict__ racc,
                      const float* __restrict__ cpr, const float* __restrict__ sv,
                      const float* __restrict__ log_lam, const float* __restrict__ log_b,
                      const float* __restrict__ cvec, const float* __restrict__ log_d_unused,
                      const float* __restrict__ log_step, const float* __restrict__ vol_gate,
                      const float* __restrict__ ln_g, const float* __restrict__ ln_b,
                      float* __restrict__ ys) {
  int blk = blockIdx.x; int b = blk / DD; int i = blk % DD;
  int n = threadIdx.x;
  float st = expf(log_step[0]);
  float lam = -expf(log_lam[n]);
  float ad = (2.f + st * lam) / (2.f - st * lam);
  float bd = st * (1.f + ad) * expf(log_b[n]) * 0.5f;
  float vg = 1.f / (1.f + expf(-vol_gate[n]));
  float g = ln_g[n], be = ln_b[n], cn = cvec[n];
  float cprv = cpr[b * DD + i];
  float h = 0.f;
  for (int s = 0; s < SS; ++s) {
    int bs = b * SS + s;
    float u = (fmaf(fcum[bs], cprv, racc[bs * DD + i])) * (1.f / DD);
    float vol = sv[bs];
    float ht = fmaf(ad, h, bd * u);
    float s1 = wred64(ht);
    float s2 = wred64(ht * ht);
    float mu = s1 * (1.f / DD);
    float var = fmaxf(s2 * (1.f / DD) - mu * mu, 0.f);
    float hn = (ht - mu) * rsqrtf(var + 1e-5f) * g + be;
    float hv = hn / (1.f + vg * vol);
    h = hv;
    float yv = wred64(cn * hv);
    if (n == 0) ys[bs * DD + i] = yv;
  }
}

// ---------------- K6: final readout ----------------
__global__ void k_final(const float* __restrict__ qo, const float* __restrict__ oo,
                        const float* __restrict__ p2, const float* __restrict__ racc,
                        const float* __restrict__ nacc, const float* __restrict__ ys,
                        const float* __restrict__ Cp, const float* __restrict__ cpr,
                        const float* __restrict__ cpn2,
                        const float* __restrict__ fcum, const float* __restrict__ cpd,
                        const float* __restrict__ sn2,
                        const float* __restrict__ mf_a, const float* __restrict__ qsum_a,
                        const float* __restrict__ n_prev,
                        const float* __restrict__ ssm_log_d, const float* __restrict__ ssm_alpha,
                        const float* __restrict__ ln_mem_g, const float* __restrict__ ln_mem_b,
                        float* __restrict__ out) {
  int bs = blockIdx.x; int b = bs / SS;
  int i = threadIdx.x;
  __shared__ float qv[DD];
  float qi = qo[bs * DD + i];
  qv[i] = qi;
  __syncthreads();
  float P1 = 0.f;
  const float* cr = Cp + (b * DD + i) * DD;
#pragma unroll
  for (int j = 0; j < DD; ++j) P1 = fmaf(cr[j], qv[j], P1);
  float fc = fcum[bs];
  float p = fmaf(fc, P1, p2[bs * DD + i]);
  float r = fmaf(fc, cpr[b * DD + i], racc[bs * DD + i]);
  float R2 = fc * fc * cpn2[b] + 2.f * fc * cpd[bs] + sn2[bs];
  float al = 1.f / (1.f + expf(-ssm_alpha[0]));
  float kap = al + (1.f - al) * expf(ssm_log_d[0]);
  float mfv = mf_a[bs];
  float beta = 1.f + mfv * (kap - 1.f);
  float gam = mfv * (1.f - al);
  float y = ys[bs * DD + i];
  float syr = wred64(y * r);
  float sy2 = wred64(y * y);
  float nrm2 = fmaxf(beta * beta * R2 + 2.f * beta * gam * syr + gam * gam * (float)DD * sy2, 0.f);
  float scale = 8.f / (sqrtf(nrm2) + 1e-6f);
  float nt = fmaf(fc, n_prev[b * DD + i], nacc[bs * DD + i]);
  float ndp = wred64(nt * qi);
  float denom = fmaxf(fabsf(ndp), 1.f);
  float hh = scale * (fmaf(beta, p, gam * y * qsum_a[bs])) / denom;
  float s1 = wred64(hh), s2 = wred64(hh * hh);
  float mu = s1 * (1.f / DD);
  float var = fmaxf(s2 * (1.f / DD) - mu * mu, 0.f);
  float o = (hh - mu) * rsqrtf(var + 1e-5f) * ln_mem_g[i] + ln_mem_b[i];
  out[bs * DD + i] = oo[bs * DD + i] * o;
}

extern "C" void kernel_launch(void* const* d_in, const int* in_sizes, int n_in,
                              void* d_out, int out_size, void* d_ws, size_t ws_size,
                              hipStream_t stream) {
  const float* x        = (const float*)d_in[0];
  const float* C_prev   = (const float*)d_in[1];
  const float* n_prev   = (const float*)d_in[2];
  const float* m_prev   = (const float*)d_in[3];
  const float* ln_in_g  = (const float*)d_in[4];
  const float* ln_in_b  = (const float*)d_in[5];
  const float* wq = (const float*)d_in[6];  const float* bq = (const float*)d_in[7];
  const float* wk = (const float*)d_in[8];  const float* bk = (const float*)d_in[9];
  const float* wv = (const float*)d_in[10]; const float* bv = (const float*)d_in[11];
  const float* wi = (const float*)d_in[12]; const float* bi = (const float*)d_in[13];
  const float* wf = (const float*)d_in[14]; const float* bf = (const float*)d_in[15];
  const float* wo = (const float*)d_in[16]; const float* bo = (const float*)d_in[17];
  const float* rd_w1 = (const float*)d_in[18]; const float* rd_b1 = (const float*)d_in[19];
  const float* rd_g  = (const float*)d_in[20]; const float* rd_be = (const float*)d_in[21];
  const float* rd_w2 = (const float*)d_in[22]; const float* rd_b2 = (const float*)d_in[23];
  const float* ssm_log_lam  = (const float*)d_in[24];
  const float* ssm_log_b    = (const float*)d_in[25];
  const float* ssm_c        = (const float*)d_in[26];
  const float* ssm_log_d    = (const float*)d_in[27];
  const float* ssm_log_step = (const float*)d_in[28];
  const float* ssm_vol_gate = (const float*)d_in[29];
  const float* ssm_alpha    = (const float*)d_in[30];
  const float* ssm_ln_g     = (const float*)d_in[31];
  const float* ssm_ln_b     = (const float*)d_in[32];
  const float* ln_mem_g     = (const float*)d_in[33];
  const float* ln_mem_b     = (const float*)d_in[34];
  float* out = (float*)d_out;

  // workspace carve (floats); total ~2.93M floats = 11.7 MB
  float* W = (float*)d_ws;
  size_t o0 = 0;
  const size_t BS = (size_t)BB * SS, BSD = BS * DD;
  float* sv   = W + o0; o0 += BS;
  float* qo   = W + o0; o0 += BSD;
  float* kno  = W + o0; o0 += BSD;
  float* vno  = W + o0; o0 += BSD;
  float* iko  = W + o0; o0 += BSD;
  float* oo   = W + o0; o0 += BSD;
  float* knT  = W + o0; o0 += BSD;
  float* vnT  = W + o0; o0 += BSD;
  float* p2   = W + o0; o0 += BSD;
  float* racc = W + o0; o0 += BSD;
  float* nacc = W + o0; o0 += BSD;
  float* ysb  = W + o0; o0 += BSD;
  float* cg_a = W + o0; o0 += BS;
  float* fg_a = W + o0; o0 += BS;
  float* mf_a = W + o0; o0 += BS;
  float* cks  = W + o0; o0 += BS;
  float* qsum = W + o0; o0 += BS;
  float* zc   = W + o0; o0 += BS;
  float* fcum = W + o0; o0 += BS;
  float* cpd  = W + o0; o0 += BS;
  float* rho  = W + o0; o0 += BS;
  float* sn2  = W + o0; o0 += BS;
  float* cpr  = W + o0; o0 += (size_t)BB * DD;
  float* cpn2 = W + o0; o0 += BB;

  hipLaunchKernelGGL(k_vol, dim3(BB), dim3(64), 0, stream, x, sv);
  hipLaunchKernelGGL(k_proj, dim3(BB * SS), dim3(64), 0, stream,
                     x, m_prev, ln_in_g, ln_in_b, wq, bq, wk, bk, wv, bv, wi, bi,
                     wf, bf, wo, bo, rd_w1, rd_b1, rd_g, rd_be, rd_w2, rd_b2,
                     qo, kno, vno, iko, oo, knT, vnT, cg_a, fg_a, mf_a, cks, qsum);
  hipLaunchKernelGGL(k_zc, dim3(BB * SS), dim3(64), 0, stream, kno, vno, C_prev, cg_a, zc);
  hipLaunchKernelGGL(k_scan, dim3(BB), dim3(64), 0, stream,
                     C_prev, iko, vno, fg_a, cks, zc, nacc, racc, fcum, cpd, cpr, cpn2);
  hipLaunchKernelGGL(k_main, dim3(BB * SS), dim3(64), 0, stream,
                     qo, kno, vno, knT, vnT, cg_a, p2, rho);
  hipLaunchKernelGGL(k_sn2, dim3(1), dim3(64), 0, stream, rho, sn2);
  hipLaunchKernelGGL(k_ssm, dim3(BB * DD), dim3(64), 0, stream,
                     fcum, racc, cpr, sv, ssm_log_lam, ssm_log_b, ssm_c, ssm_log_d,
                     ssm_log_step, ssm_vol_gate, ssm_ln_g, ssm_ln_b, ysb);
  hipLaunchKernelGGL(k_final, dim3(BB * SS), dim3(64), 0, stream,
                     qo, oo, p2, racc, nacc, ysb, C_prev, cpr, cpn2, fcum, cpd, sn2,
                     mf_a, qsum, n_prev, ssm_log_d, ssm_alpha, ln_mem_g, ln_mem_b, out);
}

// Round 2
// 555.628 us; speedup vs baseline: 1.9729x; 1.9729x over previous
//
#include <hip/hip_runtime.h>
#include <math.h>

// ParallelSMLSTMCell decomposed: never materialize C[B,S,D,D].
// B=8 S=512 F=32 D=64, window w=102. All f32.
#define BB 8
#define SS 512
#define FF 32
#define DD 64
#define WVOL 102

__device__ __forceinline__ float wred64(float v) {
#pragma unroll
  for (int m = 1; m < 64; m <<= 1) v += __shfl_xor(v, m, 64);
  return v;
}
__device__ __forceinline__ float wred32(float v) {
#pragma unroll
  for (int m = 1; m < 32; m <<= 1) v += __shfl_xor(v, m, 32);
  return v;
}

// ---------------- K1a: windowed std, one block per (b, s>=w-1) ----------------
__global__ void k_vol_std(const float* __restrict__ x, float* __restrict__ svraw) {
  int b = blockIdx.x; int s = WVOL - 1 + blockIdx.y;
  int lane = threadIdx.x; int f = lane & 31; int half = lane >> 5;
  const float* xb = x + (size_t)(b * SS) * FF + f;
  float wsum = 0.f, wsq = 0.f;
  int t0 = s - WVOL + 1 + half;
#pragma unroll 17
  for (int k = 0; k < WVOL / 2; ++k) {
    float xv = xb[(t0 + 2 * k) * FF];
    wsum += xv; wsq = fmaf(xv, xv, wsq);
  }
  wsum += __shfl_xor(wsum, 32); wsq += __shfl_xor(wsq, 32);
  float var = (wsq - wsum * wsum * (1.f / WVOL)) * (1.f / (WVOL - 1));
  float sd = sqrtf(fmaxf(var, 0.f));
  float m = wred32(sd) * (1.f / FF);
  if (lane == 0) svraw[b * SS + s] = m;
}

// ---------------- K1b: per-b normalize (mean over S incl. broadcast head) ----
__global__ void k_vol_norm(const float* __restrict__ svraw, float* __restrict__ sv) {
  int b = blockIdx.x; int tid = threadIdx.x;  // 512 threads
  float m0 = svraw[b * SS + WVOL - 1];
  float val = (tid < WVOL - 1) ? m0 : svraw[b * SS + tid];
  float ws = wred64(val);
  __shared__ float part[8];
  if ((tid & 63) == 0) part[tid >> 6] = ws;
  __syncthreads();
  float tot = 0.f;
#pragma unroll
  for (int i = 0; i < 8; ++i) tot += part[i];
  float inv = 1.f / (tot * (1.f / SS) + 1e-6f);
  sv[b * SS + tid] = val * inv;
}

// ---------------- K2: per-(b,s) LN + projections + gates ----------------
__global__ void k_proj(const float* __restrict__ x, const float* __restrict__ m_prev,
                       const float* __restrict__ ln_in_g, const float* __restrict__ ln_in_b,
                       const float* __restrict__ wq, const float* __restrict__ bq,
                       const float* __restrict__ wk, const float* __restrict__ bk,
                       const float* __restrict__ wv, const float* __restrict__ bv,
                       const float* __restrict__ wi, const float* __restrict__ bi,
                       const float* __restrict__ wf, const float* __restrict__ bf,
                       const float* __restrict__ wo, const float* __restrict__ bo,
                       const float* __restrict__ rd_w1, const float* __restrict__ rd_b1,
                       const float* __restrict__ rd_g, const float* __restrict__ rd_be,
                       const float* __restrict__ rd_w2, const float* __restrict__ rd_b2,
                       float* __restrict__ qo, float* __restrict__ kno, float* __restrict__ vno,
                       float* __restrict__ iko, float* __restrict__ oo,
                       float* __restrict__ knT, float* __restrict__ vnT,
                       float* __restrict__ cg_a, float* __restrict__ fg_a,
                       float* __restrict__ mf_a, float* __restrict__ cks_a,
                       float* __restrict__ qsum_a) {
  int bs = blockIdx.x; int b = bs / SS; int s = bs % SS;
  int lane = threadIdx.x;
  __shared__ float xs[FF];
  if (lane < FF) {
    float xv = x[bs * FF + lane];
    float s1 = wred32(xv);
    float s2 = wred32(xv * xv);
    float mu = s1 * (1.f / FF);
    float var = s2 * (1.f / FF) - mu * mu;
    xs[lane] = (xv - mu) * rsqrtf(var + 1e-5f) * ln_in_g[lane] + ln_in_b[lane];
  }
  __syncthreads();
  int d = lane;
  float aq = bq[d], ak = bk[d], av = bv[d], ao = bo[d], at = rd_b1[d];
#pragma unroll
  for (int f = 0; f < FF; ++f) {
    float xf = xs[f];
    aq = fmaf(xf, wq[d * FF + f], aq);
    ak = fmaf(xf, wk[d * FF + f], ak);
    av = fmaf(xf, wv[d * FF + f], av);
    ao = fmaf(xf, wo[d * FF + f], ao);
    at = fmaf(xf, rd_w1[d * FF + f], at);
  }
  float pit = 0.f, pft = 0.f;
  if (lane < FF) { pit = xs[lane] * wi[lane]; pft = xs[lane] * wf[lane]; }
  pit = wred32(pit); pft = wred32(pft);
  float itv = __shfl(pit, 0, 64) + bi[0];
  float ftv = __shfl(pft, 0, 64) + bf[0];
  // regime head: LN(D) -> gelu(exact) -> 4 logits -> softmax[0]
  float s1 = wred64(at), s2 = wred64(at * at);
  float mu = s1 * (1.f / DD);
  float var = s2 * (1.f / DD) - mu * mu;
  float tn = (at - mu) * rsqrtf(var + 1e-5f) * rd_g[d] + rd_be[d];
  float ge = 0.5f * tn * (1.f + erff(tn * 0.70710678118654752f));
  float l0 = wred64(ge * rd_w2[0 * DD + d]) + rd_b2[0];
  float l1 = wred64(ge * rd_w2[1 * DD + d]) + rd_b2[1];
  float l2 = wred64(ge * rd_w2[2 * DD + d]) + rd_b2[2];
  float l3 = wred64(ge * rd_w2[3 * DD + d]) + rd_b2[3];
  float mx = fmaxf(fmaxf(l0, l1), fmaxf(l2, l3));
  float e0 = expf(l0 - mx), e1 = expf(l1 - mx), e2 = expf(l2 - mx), e3 = expf(l3 - mx);
  float mfv = e0 / (e0 + e1 + e2 + e3);
  // normalize k, v
  float kd = ak * 0.125f;                       // k = (.)/sqrt(D)
  float kk = wred64(kd * kd);
  float knd = kd * (8.f / (sqrtf(kk) + 1e-12f));
  float vv = wred64(av * av);
  float vnd = av * (8.f / (sqrtf(vv) + 1e-6f));
  float ksum = wred64(knd);
  float qsum = wred64(aq);
  // stabilized gates
  float mp = fminf(fmaxf(m_prev[b], -100.f), 100.f);
  float mt = fmaxf(ftv, mp + ftv);
  float ig = expf(fminf(fmaxf(itv - mt, -15.f), 15.f));
  float fg = expf(fminf(fmaxf(ftv + mp - mt, -15.f), 15.f));
  float cg = fminf(ig, 1.f);
  qo[bs * DD + d] = aq;
  kno[bs * DD + d] = knd;
  vno[bs * DD + d] = vnd;
  iko[bs * DD + d] = ig * kd;
  oo[bs * DD + d] = 1.f / (1.f + expf(-ao));
  knT[(b * DD + d) * SS + s] = knd;
  vnT[(b * DD + d) * SS + s] = vnd;
  if (lane == 0) {
    cg_a[bs] = cg; fg_a[bs] = fg; mf_a[bs] = mfv;
    cks_a[bs] = cg * ksum; qsum_a[bs] = qsum;
  }
}

// ---------------- K3a: zc[b,t] = cg_t * vn^T Cp kn ----------------
__global__ void k_zc(const float* __restrict__ kno, const float* __restrict__ vno,
                     const float* __restrict__ Cp, const float* __restrict__ cg_a,
                     float* __restrict__ zc) {
  int bs = blockIdx.x; int b = bs / SS;
  int i = threadIdx.x;
  __shared__ float ks[DD];
  ks[i] = kno[bs * DD + i];
  __syncthreads();
  float acc = 0.f;
  const float* cr = Cp + (b * DD + i) * DD;
#pragma unroll
  for (int j = 0; j < DD; ++j) acc = fmaf(cr[j], ks[j], acc);
  float z = wred64(vno[bs * DD + i] * acc);
  if (i == 0) zc[bs] = cg_a[bs] * z;
}

// ---------------- K4: O(S^2) linear-attn p2 + Gram rho ----------------
__global__ void k_main(const float* __restrict__ qo, const float* __restrict__ kno,
                       const float* __restrict__ vno,
                       const float* __restrict__ knT, const float* __restrict__ vnT,
                       const float* __restrict__ cg_a,
                       float* __restrict__ p2, float* __restrict__ rho) {
  int bs = blockIdx.x; int b = bs / SS; int s = bs % SS;
  int lane = threadIdx.x;
  __shared__ float w[64];
  const float* qrow = qo + bs * DD;   // wave-uniform -> s_load
  const float* krow = kno + bs * DD;
  const float* vrow = vno + bs * DD;
  float pacc = 0.f, rp = 0.f;
  int ntile = s / 64 + 1;
  for (int T = 0; T < ntile * 64; T += 64) {
    int t = T + lane;
    float A = 0.f, KK = 0.f, VV = 0.f;
#pragma unroll 8
    for (int j = 0; j < DD; ++j) {
      float kt = knT[(b * DD + j) * SS + t];   // coalesced over lanes
      float vt = vnT[(b * DD + j) * SS + t];
      A = fmaf(kt, qrow[j], A);
      KK = fmaf(kt, krow[j], KK);
      VV = fmaf(vt, vrow[j], VV);
    }
    float cgt = cg_a[b * SS + t];
    w[lane] = (t <= s) ? cgt * A : 0.f;
    float wr = (t < s) ? 2.f : (t == s ? 1.f : 0.f);
    rp = fmaf(wr * cgt, KK * VV, rp);
    __syncthreads();
    int tmax = min(63, s - T);
    for (int tl = 0; tl <= tmax; ++tl) {
      float wt = w[tl];
      float vnv = vno[(b * SS + T + tl) * DD + lane];  // coalesced
      pacc = fmaf(wt, vnv, pacc);
    }
    __syncthreads();
  }
  p2[bs * DD + lane] = pacc;
  float rr = wred64(rp);
  if (lane == 0) rho[bs] = cg_a[bs] * rr;
}

// ---------------- K5a: per-b scalar shfl-scans (fcum, cpd, sn2) + Cp prep ----
__global__ void k_scalar_scan(const float* __restrict__ fg_a, const float* __restrict__ zc,
                              const float* __restrict__ rho, const float* __restrict__ Cp,
                              float* __restrict__ fcum, float* __restrict__ cpd,
                              float* __restrict__ sn2, float* __restrict__ cpr,
                              float* __restrict__ cpn2) {
  int b = blockIdx.x; int lane = threadIdx.x;
  // C_prev row sums / Frobenius^2
  float rs = 0.f, r2 = 0.f;
  const float* cr = Cp + (b * DD + lane) * DD;
#pragma unroll
  for (int j = 0; j < DD; ++j) { float c = cr[j]; rs += c; r2 = fmaf(c, c, r2); }
  cpr[b * DD + lane] = rs;
  float tot2 = wred64(r2);
  if (lane == 0) cpn2[b] = tot2;
  // chunked inclusive scans: product(fg), sum(zc), sum(rho)
  float cf = 1.f, cz = 0.f, crr = 0.f;
  for (int c = 0; c < 8; ++c) {
    int bs = b * SS + c * 64 + lane;
    float f = fg_a[bs], z = zc[bs], r = rho[bs];
#pragma unroll
    for (int m = 1; m < 64; m <<= 1) {
      float tf = __shfl_up(f, m); float tz = __shfl_up(z, m); float tr = __shfl_up(r, m);
      if (lane >= m) { f *= tf; z += tz; r += tr; }
    }
    f *= cf; z += cz; r += crr;
    fcum[bs] = f; cpd[bs] = z; sn2[bs] = r;
    cf = __shfl(f, 63); cz = __shfl(z, 63); crr = __shfl(r, 63);
  }
}

// ---------------- K5b: vector cumsums nacc/racc, 8-wave two-pass scan -------
__global__ void k_scan_vec(const float* __restrict__ ik, const float* __restrict__ vno,
                           const float* __restrict__ cks_a,
                           float* __restrict__ nacc, float* __restrict__ racc) {
  int b = blockIdx.x;
  int w = threadIdx.x >> 6, d = threadIdx.x & 63;
  __shared__ float T[2][8][DD];
  float na = 0.f, ra = 0.f;
  int s0 = w * 64;
  for (int t = 0; t < 64; ++t) {
    int bs = b * SS + s0 + t;
    na += ik[bs * DD + d];
    ra = fmaf(cks_a[bs], vno[bs * DD + d], ra);
  }
  T[0][w][d] = na; T[1][w][d] = ra;
  __syncthreads();
  na = 0.f; ra = 0.f;
  for (int w2 = 0; w2 < w; ++w2) { na += T[0][w2][d]; ra += T[1][w2][d]; }
  for (int t = 0; t < 64; ++t) {
    int bs = b * SS + s0 + t;
    na += ik[bs * DD + d];
    ra = fmaf(cks_a[bs], vno[bs * DD + d], ra);
    nacc[bs * DD + d] = na;
    racc[bs * DD + d] = ra;
  }
}

// ---------------- K6: SSM scan, one wave per (b, row i) ----------------
__global__ void k_ssm(const float* __restrict__ fcum, const float* __restrict__ racc,
                      const float* __restrict__ cpr, const float* __restrict__ sv,
                      const float* __restrict__ log_lam, const float* __restrict__ log_b,
                      const float* __restrict__ cvec,
                      const float* __restrict__ log_step, const float* __restrict__ vol_gate,
                      const float* __restrict__ ln_g, const float* __restrict__ ln_b,
                      float* __restrict__ ys) {
  int blk = blockIdx.x; int b = blk >> 6; int i = blk & 63;
  int n = threadIdx.x;
  float st = expf(log_step[0]);
  float lam = -expf(log_lam[n]);
  float ad = (2.f + st * lam) / (2.f - st * lam);
  float bd = st * (1.f + ad) * expf(log_b[n]) * 0.5f;
  float vg = 1.f / (1.f + expf(-vol_gate[n]));
  float g = ln_g[n], be = ln_b[n], cn = cvec[n];
  float cprv = cpr[b * DD + i];
  __shared__ float uv[2 * SS];
#pragma unroll
  for (int c = 0; c < 8; ++c) {
    int s = c * 64 + n; int bs = b * SS + s;
    uv[2 * s] = fmaf(fcum[bs], cprv, racc[(size_t)bs * DD + i]) * (1.f / DD);
    uv[2 * s + 1] = sv[bs];
  }
  __syncthreads();
  const float2* uvp = (const float2*)uv;
  float h = 0.f;
  for (int s = 0; s < SS; ++s) {
    float2 uu = uvp[s];               // uniform-addr ds_read_b64 broadcast
    float ht = fmaf(ad, h, bd * uu.x);
    float s1 = ht, s2 = ht * ht;
#pragma unroll
    for (int m = 1; m < 64; m <<= 1) { s1 += __shfl_xor(s1, m); s2 += __shfl_xor(s2, m); }
    float mu = s1 * (1.f / DD);
    float var = fmaxf(s2 * (1.f / DD) - mu * mu, 0.f);
    float hn = fmaf((ht - mu) * rsqrtf(var + 1e-5f), g, be);
    float hv = __fdividef(hn, fmaf(vg, uu.y, 1.f));
    h = hv;
    float yv = wred64(cn * hv);
    if (n == 0) ys[(size_t)(b * SS + s) * DD + i] = yv;
  }
}

// ---------------- K7: final readout ----------------
__global__ void k_final(const float* __restrict__ qo, const float* __restrict__ oo,
                        const float* __restrict__ p2, const float* __restrict__ racc,
                        const float* __restrict__ nacc, const float* __restrict__ ys,
                        const float* __restrict__ Cp, const float* __restrict__ cpr,
                        const float* __restrict__ cpn2,
                        const float* __restrict__ fcum, const float* __restrict__ cpd,
                        const float* __restrict__ sn2,
                        const float* __restrict__ mf_a, const float* __restrict__ qsum_a,
                        const float* __restrict__ n_prev,
                        const float* __restrict__ ssm_log_d, const float* __restrict__ ssm_alpha,
                        const float* __restrict__ ln_mem_g, const float* __restrict__ ln_mem_b,
                        float* __restrict__ out) {
  int bs = blockIdx.x; int b = bs / SS;
  int i = threadIdx.x;
  __shared__ float qv[DD];
  float qi = qo[bs * DD + i];
  qv[i] = qi;
  __syncthreads();
  float P1 = 0.f;
  const float* cr = Cp + (b * DD + i) * DD;
#pragma unroll
  for (int j = 0; j < DD; ++j) P1 = fmaf(cr[j], qv[j], P1);
  float fc = fcum[bs];
  float p = fmaf(fc, P1, p2[bs * DD + i]);
  float r = fmaf(fc, cpr[b * DD + i], racc[bs * DD + i]);
  float R2 = fc * fc * cpn2[b] + 2.f * fc * cpd[bs] + sn2[bs];
  float al = 1.f / (1.f + expf(-ssm_alpha[0]));
  float kap = al + (1.f - al) * expf(ssm_log_d[0]);
  float mfv = mf_a[bs];
  float beta = 1.f + mfv * (kap - 1.f);
  float gam = mfv * (1.f - al);
  float y = ys[bs * DD + i];
  float syr = wred64(y * r);
  float sy2 = wred64(y * y);
  float nrm2 = fmaxf(beta * beta * R2 + 2.f * beta * gam * syr + gam * gam * (float)DD * sy2, 0.f);
  float scale = 8.f / (sqrtf(nrm2) + 1e-6f);
  float nt = fmaf(fc, n_prev[b * DD + i], nacc[bs * DD + i]);
  float ndp = wred64(nt * qi);
  float denom = fmaxf(fabsf(ndp), 1.f);
  float hh = scale * (fmaf(beta, p, gam * y * qsum_a[bs])) / denom;
  float s1 = wred64(hh), s2 = wred64(hh * hh);
  float mu = s1 * (1.f / DD);
  float var = fmaxf(s2 * (1.f / DD) - mu * mu, 0.f);
  float o = (hh - mu) * rsqrtf(var + 1e-5f) * ln_mem_g[i] + ln_mem_b[i];
  out[bs * DD + i] = oo[bs * DD + i] * o;
}

extern "C" void kernel_launch(void* const* d_in, const int* in_sizes, int n_in,
                              void* d_out, int out_size, void* d_ws, size_t ws_size,
                              hipStream_t stream) {
  const float* x        = (const float*)d_in[0];
  const float* C_prev   = (const float*)d_in[1];
  const float* n_prev   = (const float*)d_in[2];
  const float* m_prev   = (const float*)d_in[3];
  const float* ln_in_g  = (const float*)d_in[4];
  const float* ln_in_b  = (const float*)d_in[5];
  const float* wq = (const float*)d_in[6];  const float* bq = (const float*)d_in[7];
  const float* wk = (const float*)d_in[8];  const float* bk = (const float*)d_in[9];
  const float* wv = (const float*)d_in[10]; const float* bv = (const float*)d_in[11];
  const float* wi = (const float*)d_in[12]; const float* bi = (const float*)d_in[13];
  const float* wf = (const float*)d_in[14]; const float* bf = (const float*)d_in[15];
  const float* wo = (const float*)d_in[16]; const float* bo = (const float*)d_in[17];
  const float* rd_w1 = (const float*)d_in[18]; const float* rd_b1 = (const float*)d_in[19];
  const float* rd_g  = (const float*)d_in[20]; const float* rd_be = (const float*)d_in[21];
  const float* rd_w2 = (const float*)d_in[22]; const float* rd_b2 = (const float*)d_in[23];
  const float* ssm_log_lam  = (const float*)d_in[24];
  const float* ssm_log_b    = (const float*)d_in[25];
  const float* ssm_c        = (const float*)d_in[26];
  const float* ssm_log_d    = (const float*)d_in[27];
  const float* ssm_log_step = (const float*)d_in[28];
  const float* ssm_vol_gate = (const float*)d_in[29];
  const float* ssm_alpha    = (const float*)d_in[30];
  const float* ssm_ln_g     = (const float*)d_in[31];
  const float* ssm_ln_b     = (const float*)d_in[32];
  const float* ln_mem_g     = (const float*)d_in[33];
  const float* ln_mem_b     = (const float*)d_in[34];
  float* out = (float*)d_out;

  float* W = (float*)d_ws;
  size_t o0 = 0;
  const size_t BS = (size_t)BB * SS, BSD = BS * DD;
  float* sv    = W + o0; o0 += BS;
  float* svraw = W + o0; o0 += BS;
  float* qo   = W + o0; o0 += BSD;
  float* kno  = W + o0; o0 += BSD;
  float* vno  = W + o0; o0 += BSD;
  float* iko  = W + o0; o0 += BSD;
  float* oo   = W + o0; o0 += BSD;
  float* knT  = W + o0; o0 += BSD;
  float* vnT  = W + o0; o0 += BSD;
  float* p2   = W + o0; o0 += BSD;
  float* racc = W + o0; o0 += BSD;
  float* nacc = W + o0; o0 += BSD;
  float* ysb  = W + o0; o0 += BSD;
  float* cg_a = W + o0; o0 += BS;
  float* fg_a = W + o0; o0 += BS;
  float* mf_a = W + o0; o0 += BS;
  float* cks  = W + o0; o0 += BS;
  float* qsum = W + o0; o0 += BS;
  float* zc   = W + o0; o0 += BS;
  float* fcum = W + o0; o0 += BS;
  float* cpd  = W + o0; o0 += BS;
  float* rho  = W + o0; o0 += BS;
  float* sn2  = W + o0; o0 += BS;
  float* cpr  = W + o0; o0 += (size_t)BB * DD;
  float* cpn2 = W + o0; o0 += BB;

  hipLaunchKernelGGL(k_vol_std, dim3(BB, SS - WVOL + 1), dim3(64), 0, stream, x, svraw);
  hipLaunchKernelGGL(k_vol_norm, dim3(BB), dim3(SS), 0, stream, svraw, sv);
  hipLaunchKernelGGL(k_proj, dim3(BB * SS), dim3(64), 0, stream,
                     x, m_prev, ln_in_g, ln_in_b, wq, bq, wk, bk, wv, bv, wi, bi,
                     wf, bf, wo, bo, rd_w1, rd_b1, rd_g, rd_be, rd_w2, rd_b2,
                     qo, kno, vno, iko, oo, knT, vnT, cg_a, fg_a, mf_a, cks, qsum);
  hipLaunchKernelGGL(k_zc, dim3(BB * SS), dim3(64), 0, stream, kno, vno, C_prev, cg_a, zc);
  hipLaunchKernelGGL(k_main, dim3(BB * SS), dim3(64), 0, stream,
                     qo, kno, vno, knT, vnT, cg_a, p2, rho);
  hipLaunchKernelGGL(k_scalar_scan, dim3(BB), dim3(64), 0, stream,
                     fg_a, zc, rho, C_prev, fcum, cpd, sn2, cpr, cpn2);
  hipLaunchKernelGGL(k_scan_vec, dim3(BB), dim3(512), 0, stream,
                     iko, vno, cks, nacc, racc);
  hipLaunchKernelGGL(k_ssm, dim3(BB * DD), dim3(64), 0, stream,
                     fcum, racc, cpr, sv, ssm_log_lam, ssm_log_b, ssm_c,
                     ssm_log_step, ssm_vol_gate, ssm_ln_g, ssm_ln_b, ysb);
  hipLaunchKernelGGL(k_final, dim3(BB * SS), dim3(64), 0, stream,
                     qo, oo, p2, racc, nacc, ysb, C_prev, cpr, cpn2, fcum, cpd, sn2,
                     mf_a, qsum, n_prev, ssm_log_d, ssm_alpha, ln_mem_g, ln_mem_b, out);
}

// Round 4
// 364.973 us; speedup vs baseline: 3.0035x; 1.5224x over previous
//
#include <hip/hip_runtime.h>
#include <math.h>

// ParallelSMLSTMCell decomposed: never materialize C[B,S,D,D].
// B=8 S=512 F=32 D=64, window w=102. All f32.
// All cross-lane reductions/scans are DPP-based (VALU-only): hipcc lowers
// __shfl_* to DS ops (~120cy latency each) which made the serial SSM scan
// ~1300cy/step at 2 waves/CU (round-2 profile).
// (Round-3 submission never ran: container-acquire infra failure. Identical
// source resubmitted as the retry A/B.)
#define BB 8
#define SS 512
#define FF 32
#define DD 64
#define WVOL 102

template<int CTRL, int RM, bool BC>
__device__ __forceinline__ float updpp(float oldv, float x) {
  return __int_as_float(__builtin_amdgcn_update_dpp(
      __float_as_int(oldv), __float_as_int(x), CTRL, RM, 0xF, BC));
}
__device__ __forceinline__ float rlane(float v, int l) {
  return __int_as_float(__builtin_amdgcn_readlane(__float_as_int(v), l));
}
// wave64 sum, broadcast to all lanes (readlane 63 -> sgpr)
__device__ __forceinline__ float dsum64(float x) {
  x += updpp<0x111, 0xF, true>(0.f, x);  // row_shr:1
  x += updpp<0x112, 0xF, true>(0.f, x);  // row_shr:2
  x += updpp<0x114, 0xF, true>(0.f, x);  // row_shr:4
  x += updpp<0x118, 0xF, true>(0.f, x);  // row_shr:8
  x += updpp<0x142, 0xF, true>(0.f, x);  // row_bcast:15
  x += updpp<0x143, 0xF, true>(0.f, x);  // row_bcast:31
  return rlane(x, 63);
}
// sum over lanes 0-31 (upper half may hold garbage/duplicates), broadcast
__device__ __forceinline__ float dsum32(float x) {
  x += updpp<0x111, 0xF, true>(0.f, x);
  x += updpp<0x112, 0xF, true>(0.f, x);
  x += updpp<0x114, 0xF, true>(0.f, x);
  x += updpp<0x118, 0xF, true>(0.f, x);
  x += updpp<0x142, 0xF, true>(0.f, x);  // lane31 = sum(0..31)
  return rlane(x, 31);
}
// wave64 inclusive scans (Kogge-Stone via DPP)
__device__ __forceinline__ float dscan_add(float x) {
  x += updpp<0x111, 0xF, true>(0.f, x);
  x += updpp<0x112, 0xF, true>(0.f, x);
  x += updpp<0x114, 0xF, true>(0.f, x);
  x += updpp<0x118, 0xF, true>(0.f, x);
  x += updpp<0x142, 0xA, true>(0.f, x);  // rows 1,3 += lane15/47
  x += updpp<0x143, 0xC, true>(0.f, x);  // rows 2,3 += lane31
  return x;
}
__device__ __forceinline__ float dscan_mul(float x) {
  x *= updpp<0x111, 0xF, false>(1.f, x);
  x *= updpp<0x112, 0xF, false>(1.f, x);
  x *= updpp<0x114, 0xF, false>(1.f, x);
  x *= updpp<0x118, 0xF, false>(1.f, x);
  x *= updpp<0x142, 0xA, false>(1.f, x);
  x *= updpp<0x143, 0xC, false>(1.f, x);
  return x;
}

// ---------------- K1a: windowed std, one block per (b, s>=w-1) ----------------
__global__ void k_vol_std(const float* __restrict__ x, float* __restrict__ svraw) {
  int b = blockIdx.x; int s = WVOL - 1 + blockIdx.y;
  int lane = threadIdx.x; int f = lane & 31; int half = lane >> 5;
  const float* xb = x + (size_t)(b * SS) * FF + f;
  float wsum = 0.f, wsq = 0.f;
  int t0 = s - WVOL + 1 + half;
#pragma unroll 17
  for (int k = 0; k < WVOL / 2; ++k) {
    float xv = xb[(t0 + 2 * k) * FF];
    wsum += xv; wsq = fmaf(xv, xv, wsq);
  }
  wsum += __shfl_xor(wsum, 32); wsq += __shfl_xor(wsq, 32);
  float var = (wsq - wsum * wsum * (1.f / WVOL)) * (1.f / (WVOL - 1));
  float sd = sqrtf(fmaxf(var, 0.f));
  float m = dsum64(sd) * 0.5f * (1.f / FF);  // halves duplicated -> /2
  if (lane == 0) svraw[b * SS + s] = m;
}

// ---------------- K1b: per-b normalize ----------------
__global__ void k_vol_norm(const float* __restrict__ svraw, float* __restrict__ sv) {
  int b = blockIdx.x; int tid = threadIdx.x;  // 512 threads
  float m0 = svraw[b * SS + WVOL - 1];
  float val = (tid < WVOL - 1) ? m0 : svraw[b * SS + tid];
  float ws = dsum64(val);
  __shared__ float part[8];
  if ((tid & 63) == 0) part[tid >> 6] = ws;
  __syncthreads();
  float tot = 0.f;
#pragma unroll
  for (int i = 0; i < 8; ++i) tot += part[i];
  float inv = 1.f / (tot * (1.f / SS) + 1e-6f);
  sv[b * SS + tid] = val * inv;
}

// ---------------- K2: per-(b,s) LN + projections + gates ----------------
__global__ void k_proj(const float* __restrict__ x, const float* __restrict__ m_prev,
                       const float* __restrict__ ln_in_g, const float* __restrict__ ln_in_b,
                       const float* __restrict__ wq, const float* __restrict__ bq,
                       const float* __restrict__ wk, const float* __restrict__ bk,
                       const float* __restrict__ wv, const float* __restrict__ bv,
                       const float* __restrict__ wi, const float* __restrict__ bi,
                       const float* __restrict__ wf, const float* __restrict__ bf,
                       const float* __restrict__ wo, const float* __restrict__ bo,
                       const float* __restrict__ rd_w1, const float* __restrict__ rd_b1,
                       const float* __restrict__ rd_g, const float* __restrict__ rd_be,
                       const float* __restrict__ rd_w2, const float* __restrict__ rd_b2,
                       float* __restrict__ qo, float* __restrict__ kno, float* __restrict__ vno,
                       float* __restrict__ iko, float* __restrict__ oo,
                       float* __restrict__ knT, float* __restrict__ vnT,
                       float* __restrict__ cg_a, float* __restrict__ fg_a,
                       float* __restrict__ mf_a, float* __restrict__ cks_a,
                       float* __restrict__ qsum_a) {
  int bs = blockIdx.x; int b = bs / SS; int s = bs % SS;
  int lane = threadIdx.x;
  __shared__ float xs[FF];
  float xv = (lane < FF) ? x[bs * FF + lane] : 0.f;
  float s1x = dsum32(xv);
  float s2x = dsum32(xv * xv);
  if (lane < FF) {
    float mu = s1x * (1.f / FF);
    float var = s2x * (1.f / FF) - mu * mu;
    xs[lane] = (xv - mu) * rsqrtf(var + 1e-5f) * ln_in_g[lane] + ln_in_b[lane];
  }
  __syncthreads();
  int d = lane;
  float aq = bq[d], ak = bk[d], av = bv[d], ao = bo[d], at = rd_b1[d];
#pragma unroll
  for (int f = 0; f < FF; ++f) {
    float xf = xs[f];
    aq = fmaf(xf, wq[d * FF + f], aq);
    ak = fmaf(xf, wk[d * FF + f], ak);
    av = fmaf(xf, wv[d * FF + f], av);
    ao = fmaf(xf, wo[d * FF + f], ao);
    at = fmaf(xf, rd_w1[d * FF + f], at);
  }
  float pit = (lane < FF) ? xs[lane] * wi[lane] : 0.f;
  float pft = (lane < FF) ? xs[lane] * wf[lane] : 0.f;
  float itv = dsum32(pit) + bi[0];
  float ftv = dsum32(pft) + bf[0];
  // regime head: LN(D) -> gelu(exact) -> 4 logits -> softmax[0]
  float s1 = dsum64(at), s2 = dsum64(at * at);
  float mu = s1 * (1.f / DD);
  float var = s2 * (1.f / DD) - mu * mu;
  float tn = (at - mu) * rsqrtf(var + 1e-5f) * rd_g[d] + rd_be[d];
  float ge = 0.5f * tn * (1.f + erff(tn * 0.70710678118654752f));
  float l0 = dsum64(ge * rd_w2[0 * DD + d]) + rd_b2[0];
  float l1 = dsum64(ge * rd_w2[1 * DD + d]) + rd_b2[1];
  float l2 = dsum64(ge * rd_w2[2 * DD + d]) + rd_b2[2];
  float l3 = dsum64(ge * rd_w2[3 * DD + d]) + rd_b2[3];
  float mx = fmaxf(fmaxf(l0, l1), fmaxf(l2, l3));
  float e0 = expf(l0 - mx), e1 = expf(l1 - mx), e2 = expf(l2 - mx), e3 = expf(l3 - mx);
  float mfv = e0 / (e0 + e1 + e2 + e3);
  // normalize k, v
  float kd = ak * 0.125f;
  float kk = dsum64(kd * kd);
  float knd = kd * (8.f / (sqrtf(kk) + 1e-12f));
  float vv = dsum64(av * av);
  float vnd = av * (8.f / (sqrtf(vv) + 1e-6f));
  float ksum = dsum64(knd);
  float qsum = dsum64(aq);
  // stabilized gates
  float mp = fminf(fmaxf(m_prev[b], -100.f), 100.f);
  float mt = fmaxf(ftv, mp + ftv);
  float ig = expf(fminf(fmaxf(itv - mt, -15.f), 15.f));
  float fg = expf(fminf(fmaxf(ftv + mp - mt, -15.f), 15.f));
  float cg = fminf(ig, 1.f);
  qo[bs * DD + d] = aq;
  kno[bs * DD + d] = knd;
  vno[bs * DD + d] = vnd;
  iko[bs * DD + d] = ig * kd;
  oo[bs * DD + d] = 1.f / (1.f + expf(-ao));
  knT[(b * DD + d) * SS + s] = knd;
  vnT[(b * DD + d) * SS + s] = vnd;
  if (lane == 0) {
    cg_a[bs] = cg; fg_a[bs] = fg; mf_a[bs] = mfv;
    cks_a[bs] = cg * ksum; qsum_a[bs] = qsum;
  }
}

// ---------------- K3a: zc[b,t] = cg_t * vn^T Cp kn ----------------
__global__ void k_zc(const float* __restrict__ kno, const float* __restrict__ vno,
                     const float* __restrict__ Cp, const float* __restrict__ cg_a,
                     float* __restrict__ zc) {
  int bs = blockIdx.x; int b = bs / SS;
  int i = threadIdx.x;
  __shared__ float ks[DD];
  ks[i] = kno[bs * DD + i];
  __syncthreads();
  float acc = 0.f;
  const float* cr = Cp + (b * DD + i) * DD;
#pragma unroll
  for (int j = 0; j < DD; ++j) acc = fmaf(cr[j], ks[j], acc);
  float z = dsum64(vno[bs * DD + i] * acc);
  if (i == 0) zc[bs] = cg_a[bs] * z;
}

// ---------------- K4: O(S^2) linear-attn p2 + Gram rho ----------------
__global__ void k_main(const float* __restrict__ qo, const float* __restrict__ kno,
                       const float* __restrict__ vno,
                       const float* __restrict__ knT, const float* __restrict__ vnT,
                       const float* __restrict__ cg_a,
                       float* __restrict__ p2, float* __restrict__ rho) {
  int bs = blockIdx.x; int b = bs / SS; int s = bs % SS;
  int lane = threadIdx.x;
  __shared__ float w[64];
  const float* qrow = qo + bs * DD;
  const float* krow = kno + bs * DD;
  const float* vrow = vno + bs * DD;
  float pacc = 0.f, rp = 0.f;
  int sT = s & ~63;
  // full tiles: every lane valid, inner loop fixed 64 iters (unrollable)
  for (int T = 0; T < sT; T += 64) {
    int t = T + lane;
    float A = 0.f, KK = 0.f, VV = 0.f;
#pragma unroll 8
    for (int j = 0; j < DD; ++j) {
      float kt = knT[(b * DD + j) * SS + t];
      float vt = vnT[(b * DD + j) * SS + t];
      A = fmaf(kt, qrow[j], A);
      KK = fmaf(kt, krow[j], KK);
      VV = fmaf(vt, vrow[j], VV);
    }
    float cgt = cg_a[b * SS + t];
    w[lane] = cgt * A;
    rp = fmaf(2.f * cgt, KK * VV, rp);
    __syncthreads();
#pragma unroll 8
    for (int tl = 0; tl < 64; ++tl)
      pacc = fmaf(w[tl], vno[(b * SS + T + tl) * DD + lane], pacc);
    __syncthreads();
  }
  // partial tile containing s
  {
    int T = sT; int t = T + lane;
    float A = 0.f, KK = 0.f, VV = 0.f;
#pragma unroll 8
    for (int j = 0; j < DD; ++j) {
      float kt = knT[(b * DD + j) * SS + t];
      float vt = vnT[(b * DD + j) * SS + t];
      A = fmaf(kt, qrow[j], A);
      KK = fmaf(kt, krow[j], KK);
      VV = fmaf(vt, vrow[j], VV);
    }
    float cgt = cg_a[b * SS + t];
    w[lane] = (t <= s) ? cgt * A : 0.f;
    float wr = (t < s) ? 2.f : (t == s ? 1.f : 0.f);
    rp = fmaf(wr * cgt, KK * VV, rp);
    __syncthreads();
    int tmax = s - sT;
    for (int tl = 0; tl <= tmax; ++tl)
      pacc = fmaf(w[tl], vno[(b * SS + T + tl) * DD + lane], pacc);
  }
  p2[bs * DD + lane] = pacc;
  float rr = dsum64(rp);
  if (lane == 0) rho[bs] = cg_a[bs] * rr;
}

// ---------------- K5a: per-b scalar DPP-scans (fcum, cpd, sn2) + Cp prep ----
__global__ void k_scalar_scan(const float* __restrict__ fg_a, const float* __restrict__ zc,
                              const float* __restrict__ rho, const float* __restrict__ Cp,
                              float* __restrict__ fcum, float* __restrict__ cpd,
                              float* __restrict__ sn2, float* __restrict__ cpr,
                              float* __restrict__ cpn2) {
  int b = blockIdx.x; int lane = threadIdx.x;
  float rs = 0.f, r2 = 0.f;
  const float* cr = Cp + (b * DD + lane) * DD;
#pragma unroll
  for (int j = 0; j < DD; ++j) { float c = cr[j]; rs += c; r2 = fmaf(c, c, r2); }
  cpr[b * DD + lane] = rs;
  float tot2 = dsum64(r2);
  if (lane == 0) cpn2[b] = tot2;
  float cf = 1.f, cz = 0.f, crr = 0.f;
  for (int c = 0; c < 8; ++c) {
    int bs = b * SS + c * 64 + lane;
    float f = dscan_mul(fg_a[bs]) * cf;
    float z = dscan_add(zc[bs]) + cz;
    float r = dscan_add(rho[bs]) + crr;
    fcum[bs] = f; cpd[bs] = z; sn2[bs] = r;
    cf = rlane(f, 63); cz = rlane(z, 63); crr = rlane(r, 63);
  }
}

// ---------------- K5b: vector cumsums nacc/racc, 8-wave two-pass scan -------
__global__ void k_scan_vec(const float* __restrict__ ik, const float* __restrict__ vno,
                           const float* __restrict__ cks_a,
                           float* __restrict__ nacc, float* __restrict__ racc) {
  int b = blockIdx.x;
  int w = threadIdx.x >> 6, d = threadIdx.x & 63;
  __shared__ float T[2][8][DD];
  float na = 0.f, ra = 0.f;
  int s0 = w * 64;
  for (int t = 0; t < 64; ++t) {
    int bs = b * SS + s0 + t;
    na += ik[bs * DD + d];
    ra = fmaf(cks_a[bs], vno[bs * DD + d], ra);
  }
  T[0][w][d] = na; T[1][w][d] = ra;
  __syncthreads();
  na = 0.f; ra = 0.f;
  for (int w2 = 0; w2 < w; ++w2) { na += T[0][w2][d]; ra += T[1][w2][d]; }
  for (int t = 0; t < 64; ++t) {
    int bs = b * SS + s0 + t;
    na += ik[bs * DD + d];
    ra = fmaf(cks_a[bs], vno[bs * DD + d], ra);
    nacc[bs * DD + d] = na;
    racc[bs * DD + d] = ra;
  }
}

// ---------------- K6: SSM scan, one wave per (b, row i); all-VALU ----------
__global__ void k_ssm(const float* __restrict__ fcum, const float* __restrict__ racc,
                      const float* __restrict__ cpr, const float* __restrict__ sv,
                      const float* __restrict__ log_lam, const float* __restrict__ log_b,
                      const float* __restrict__ cvec,
                      const float* __restrict__ log_step, const float* __restrict__ vol_gate,
                      const float* __restrict__ ln_g, const float* __restrict__ ln_b,
                      float* __restrict__ ys) {
  int blk = blockIdx.x; int b = blk >> 6; int i = blk & 63;
  int n = threadIdx.x;
  float st = expf(log_step[0]);
  float lam = -expf(log_lam[n]);
  float ad = (2.f + st * lam) / (2.f - st * lam);
  float bd = st * (1.f + ad) * expf(log_b[n]) * 0.5f;
  float vg = 1.f / (1.f + expf(-vol_gate[n]));
  float g = ln_g[n], be = ln_b[n], cn = cvec[n];
  float cprv = cpr[b * DD + i];
  // preload u/vol into registers: lane t holds step c*64+t
  float u[8], w[8];
#pragma unroll
  for (int c = 0; c < 8; ++c) {
    int s = c * 64 + n; int bs = b * SS + s;
    u[c] = fmaf(fcum[bs], cprv, racc[(size_t)bs * DD + i]) * (1.f / DD);
    w[c] = sv[bs];
  }
  float h = 0.f;
#pragma unroll
  for (int c = 0; c < 8; ++c) {
    float yreg = 0.f;
    for (int t = 0; t < 64; ++t) {
      float uu = rlane(u[c], t);            // dynamic-uniform lane: v_readlane
      float vv = rlane(w[c], t);
      float ht = fmaf(ad, h, bd * uu);
      // interleaved dual DPP reduction (sum, sumsq)
      float p1 = ht, p2 = ht * ht;
      p1 += updpp<0x111, 0xF, true>(0.f, p1); p2 += updpp<0x111, 0xF, true>(0.f, p2);
      p1 += updpp<0x112, 0xF, true>(0.f, p1); p2 += updpp<0x112, 0xF, true>(0.f, p2);
      p1 += updpp<0x114, 0xF, true>(0.f, p1); p2 += updpp<0x114, 0xF, true>(0.f, p2);
      p1 += updpp<0x118, 0xF, true>(0.f, p1); p2 += updpp<0x118, 0xF, true>(0.f, p2);
      p1 += updpp<0x142, 0xF, true>(0.f, p1); p2 += updpp<0x142, 0xF, true>(0.f, p2);
      p1 += updpp<0x143, 0xF, true>(0.f, p1); p2 += updpp<0x143, 0xF, true>(0.f, p2);
      float s1 = rlane(p1, 63), s2 = rlane(p2, 63);
      float mu = s1 * (1.f / DD);
      float var = fmaxf(s2 * (1.f / DD) - mu * mu, 0.f);
      float hn = fmaf((ht - mu) * rsqrtf(var + 1e-5f), g, be);
      float hv = __fdividef(hn, fmaf(vg, vv, 1.f));
      h = hv;
      float y = cn * hv;
      y += updpp<0x111, 0xF, true>(0.f, y);
      y += updpp<0x112, 0xF, true>(0.f, y);
      y += updpp<0x114, 0xF, true>(0.f, y);
      y += updpp<0x118, 0xF, true>(0.f, y);
      y += updpp<0x142, 0xF, true>(0.f, y);
      y += updpp<0x143, 0xF, true>(0.f, y);
      float su = rlane(y, 63);
      yreg = (n == t) ? su : yreg;          // gather y_t into lane t
    }
    ys[(size_t)(b * SS + c * 64 + n) * DD + i] = yreg;
  }
}

// ---------------- K7: final readout ----------------
__global__ void k_final(const float* __restrict__ qo, const float* __restrict__ oo,
                        const float* __restrict__ p2, const float* __restrict__ racc,
                        const float* __restrict__ nacc, const float* __restrict__ ys,
                        const float* __restrict__ Cp, const float* __restrict__ cpr,
                        const float* __restrict__ cpn2,
                        const float* __restrict__ fcum, const float* __restrict__ cpd,
                        const float* __restrict__ sn2,
                        const float* __restrict__ mf_a, const float* __restrict__ qsum_a,
                        const float* __restrict__ n_prev,
                        const float* __restrict__ ssm_log_d, const float* __restrict__ ssm_alpha,
                        const float* __restrict__ ln_mem_g, const float* __restrict__ ln_mem_b,
                        float* __restrict__ out) {
  int bs = blockIdx.x; int b = bs / SS;
  int i = threadIdx.x;
  __shared__ float qv[DD];
  float qi = qo[bs * DD + i];
  qv[i] = qi;
  __syncthreads();
  float P1 = 0.f;
  const float* cr = Cp + (b * DD + i) * DD;
#pragma unroll
  for (int j = 0; j < DD; ++j) P1 = fmaf(cr[j], qv[j], P1);
  float fc = fcum[bs];
  float p = fmaf(fc, P1, p2[bs * DD + i]);
  float r = fmaf(fc, cpr[b * DD + i], racc[bs * DD + i]);
  float R2 = fc * fc * cpn2[b] + 2.f * fc * cpd[bs] + sn2[bs];
  float al = 1.f / (1.f + expf(-ssm_alpha[0]));
  float kap = al + (1.f - al) * expf(ssm_log_d[0]);
  float mfv = mf_a[bs];
  float beta = 1.f + mfv * (kap - 1.f);
  float gam = mfv * (1.f - al);
  float y = ys[bs * DD + i];
  float syr = dsum64(y * r);
  float sy2 = dsum64(y * y);
  float nrm2 = fmaxf(beta * beta * R2 + 2.f * beta * gam * syr + gam * gam * (float)DD * sy2, 0.f);
  float scale = 8.f / (sqrtf(nrm2) + 1e-6f);
  float nt = fmaf(fc, n_prev[b * DD + i], nacc[bs * DD + i]);
  float ndp = dsum64(nt * qi);
  float denom = fmaxf(fabsf(ndp), 1.f);
  float hh = scale * (fmaf(beta, p, gam * y * qsum_a[bs])) / denom;
  float s1 = dsum64(hh), s2 = dsum64(hh * hh);
  float mu = s1 * (1.f / DD);
  float var = fmaxf(s2 * (1.f / DD) - mu * mu, 0.f);
  float o = (hh - mu) * rsqrtf(var + 1e-5f) * ln_mem_g[i] + ln_mem_b[i];
  out[bs * DD + i] = oo[bs * DD + i] * o;
}

extern "C" void kernel_launch(void* const* d_in, const int* in_sizes, int n_in,
                              void* d_out, int out_size, void* d_ws, size_t ws_size,
                              hipStream_t stream) {
  const float* x        = (const float*)d_in[0];
  const float* C_prev   = (const float*)d_in[1];
  const float* n_prev   = (const float*)d_in[2];
  const float* m_prev   = (const float*)d_in[3];
  const float* ln_in_g  = (const float*)d_in[4];
  const float* ln_in_b  = (const float*)d_in[5];
  const float* wq = (const float*)d_in[6];  const float* bq = (const float*)d_in[7];
  const float* wk = (const float*)d_in[8];  const float* bk = (const float*)d_in[9];
  const float* wv = (const float*)d_in[10]; const float* bv = (const float*)d_in[11];
  const float* wi = (const float*)d_in[12]; const float* bi = (const float*)d_in[13];
  const float* wf = (const float*)d_in[14]; const float* bf = (const float*)d_in[15];
  const float* wo = (const float*)d_in[16]; const float* bo = (const float*)d_in[17];
  const float* rd_w1 = (const float*)d_in[18]; const float* rd_b1 = (const float*)d_in[19];
  const float* rd_g  = (const float*)d_in[20]; const float* rd_be = (const float*)d_in[21];
  const float* rd_w2 = (const float*)d_in[22]; const float* rd_b2 = (const float*)d_in[23];
  const float* ssm_log_lam  = (const float*)d_in[24];
  const float* ssm_log_b    = (const float*)d_in[25];
  const float* ssm_c        = (const float*)d_in[26];
  const float* ssm_log_d    = (const float*)d_in[27];
  const float* ssm_log_step = (const float*)d_in[28];
  const float* ssm_vol_gate = (const float*)d_in[29];
  const float* ssm_alpha    = (const float*)d_in[30];
  const float* ssm_ln_g     = (const float*)d_in[31];
  const float* ssm_ln_b     = (const float*)d_in[32];
  const float* ln_mem_g     = (const float*)d_in[33];
  const float* ln_mem_b     = (const float*)d_in[34];
  float* out = (float*)d_out;

  float* W = (float*)d_ws;
  size_t o0 = 0;
  const size_t BS = (size_t)BB * SS, BSD = BS * DD;
  float* sv    = W + o0; o0 += BS;
  float* svraw = W + o0; o0 += BS;
  float* qo   = W + o0; o0 += BSD;
  float* kno  = W + o0; o0 += BSD;
  float* vno  = W + o0; o0 += BSD;
  float* iko  = W + o0; o0 += BSD;
  float* oo   = W + o0; o0 += BSD;
  float* knT  = W + o0; o0 += BSD;
  float* vnT  = W + o0; o0 += BSD;
  float* p2   = W + o0; o0 += BSD;
  float* racc = W + o0; o0 += BSD;
  float* nacc = W + o0; o0 += BSD;
  float* ysb  = W + o0; o0 += BSD;
  float* cg_a = W + o0; o0 += BS;
  float* fg_a = W + o0; o0 += BS;
  float* mf_a = W + o0; o0 += BS;
  float* cks  = W + o0; o0 += BS;
  float* qsum = W + o0; o0 += BS;
  float* zc   = W + o0; o0 += BS;
  float* fcum = W + o0; o0 += BS;
  float* cpd  = W + o0; o0 += BS;
  float* rho  = W + o0; o0 += BS;
  float* sn2  = W + o0; o0 += BS;
  float* cpr  = W + o0; o0 += (size_t)BB * DD;
  float* cpn2 = W + o0; o0 += BB;

  hipLaunchKernelGGL(k_vol_std, dim3(BB, SS - WVOL + 1), dim3(64), 0, stream, x, svraw);
  hipLaunchKernelGGL(k_vol_norm, dim3(BB), dim3(SS), 0, stream, svraw, sv);
  hipLaunchKernelGGL(k_proj, dim3(BB * SS), dim3(64), 0, stream,
                     x, m_prev, ln_in_g, ln_in_b, wq, bq, wk, bk, wv, bv, wi, bi,
                     wf, bf, wo, bo, rd_w1, rd_b1, rd_g, rd_be, rd_w2, rd_b2,
                     qo, kno, vno, iko, oo, knT, vnT, cg_a, fg_a, mf_a, cks, qsum);
  hipLaunchKernelGGL(k_zc, dim3(BB * SS), dim3(64), 0, stream, kno, vno, C_prev, cg_a, zc);
  hipLaunchKernelGGL(k_main, dim3(BB * SS), dim3(64), 0, stream,
                     qo, kno, vno, knT, vnT, cg_a, p2, rho);
  hipLaunchKernelGGL(k_scalar_scan, dim3(BB), dim3(64), 0, stream,
                     fg_a, zc, rho, C_prev, fcum, cpd, sn2, cpr, cpn2);
  hipLaunchKernelGGL(k_scan_vec, dim3(BB), dim3(512), 0, stream,
                     iko, vno, cks, nacc, racc);
  hipLaunchKernelGGL(k_ssm, dim3(BB * DD), dim3(64), 0, stream,
                     fcum, racc, cpr, sv, ssm_log_lam, ssm_log_b, ssm_c,
                     ssm_log_step, ssm_vol_gate, ssm_ln_g, ssm_ln_b, ysb);
  hipLaunchKernelGGL(k_final, dim3(BB * SS), dim3(64), 0, stream,
                     qo, oo, p2, racc, nacc, ysb, C_prev, cpr, cpn2, fcum, cpd, sn2,
                     mf_a, qsum, n_prev, ssm_log_d, ssm_alpha, ln_mem_g, ln_mem_b, out);
}

// Round 6
// 332.284 us; speedup vs baseline: 3.2989x; 1.0984x over previous
//
#include <hip/hip_runtime.h>
#include <math.h>

// ParallelSMLSTMCell decomposed: never materialize C[B,S,D,D].
// B=8 S=512 F=32 D=64, window w=102. All f32.
// Cross-lane via DPP (VALU-only). k_ssm chain trimmed: rcp/rsq as single
// v_rcp/v_rsq, divide-by-den folded to off-chain reciprocal (den is
// input-only), cndmask y-gather (NOTE: __builtin_amdgcn_writelane does not
// exist on this toolchain; readlane does), unroll-4 pipelining.
#define BB 8
#define SS 512
#define FF 32
#define DD 64
#define WVOL 102
#define CH 16
#define NCH (SS / CH)  // 32 chunks

template<int CTRL, int RM, bool BC>
__device__ __forceinline__ float updpp(float oldv, float x) {
  return __int_as_float(__builtin_amdgcn_update_dpp(
      __float_as_int(oldv), __float_as_int(x), CTRL, RM, 0xF, BC));
}
__device__ __forceinline__ float rlane(float v, int l) {
  return __int_as_float(__builtin_amdgcn_readlane(__float_as_int(v), l));
}
// wave64 sum, broadcast via SGPR
__device__ __forceinline__ float dsum64(float x) {
  x += updpp<0x111, 0xF, true>(0.f, x);  // row_shr:1
  x += updpp<0x112, 0xF, true>(0.f, x);  // row_shr:2
  x += updpp<0x114, 0xF, true>(0.f, x);  // row_shr:4
  x += updpp<0x118, 0xF, true>(0.f, x);  // row_shr:8
  x += updpp<0x142, 0xF, true>(0.f, x);  // row_bcast:15
  x += updpp<0x143, 0xF, true>(0.f, x);  // row_bcast:31
  return rlane(x, 63);
}
__device__ __forceinline__ float dsum32(float x) {
  x += updpp<0x111, 0xF, true>(0.f, x);
  x += updpp<0x112, 0xF, true>(0.f, x);
  x += updpp<0x114, 0xF, true>(0.f, x);
  x += updpp<0x118, 0xF, true>(0.f, x);
  x += updpp<0x142, 0xF, true>(0.f, x);
  return rlane(x, 31);
}
__device__ __forceinline__ float dscan_add(float x) {
  x += updpp<0x111, 0xF, true>(0.f, x);
  x += updpp<0x112, 0xF, true>(0.f, x);
  x += updpp<0x114, 0xF, true>(0.f, x);
  x += updpp<0x118, 0xF, true>(0.f, x);
  x += updpp<0x142, 0xA, true>(0.f, x);
  x += updpp<0x143, 0xC, true>(0.f, x);
  return x;
}
__device__ __forceinline__ float dscan_mul(float x) {
  x *= updpp<0x111, 0xF, false>(1.f, x);
  x *= updpp<0x112, 0xF, false>(1.f, x);
  x *= updpp<0x114, 0xF, false>(1.f, x);
  x *= updpp<0x118, 0xF, false>(1.f, x);
  x *= updpp<0x142, 0xA, false>(1.f, x);
  x *= updpp<0x143, 0xC, false>(1.f, x);
  return x;
}

// ---------------- K1: windowed std, one block per (b, s>=w-1) ----------------
__global__ void k_vol_std(const float* __restrict__ x, float* __restrict__ svraw) {
  int b = blockIdx.x; int s = WVOL - 1 + blockIdx.y;
  int lane = threadIdx.x; int f = lane & 31; int half = lane >> 5;
  const float* xb = x + (size_t)(b * SS) * FF + f;
  float wsum = 0.f, wsq = 0.f;
  int t0 = s - WVOL + 1 + half;
#pragma unroll 17
  for (int k = 0; k < WVOL / 2; ++k) {
    float xv = xb[(t0 + 2 * k) * FF];
    wsum += xv; wsq = fmaf(xv, xv, wsq);
  }
  wsum += __shfl_xor(wsum, 32); wsq += __shfl_xor(wsq, 32);
  float var = (wsq - wsum * wsum * (1.f / WVOL)) * (1.f / (WVOL - 1));
  float sd = sqrtf(fmaxf(var, 0.f));
  float m = dsum64(sd) * 0.5f * (1.f / FF);  // halves duplicated -> /2
  if (lane == 0) svraw[b * SS + s] = m;
}

// ---------------- K2: per-(b,s) LN + projections + gates + zc ----------------
__global__ void k_proj(const float* __restrict__ x, const float* __restrict__ m_prev,
                       const float* __restrict__ Cp,
                       const float* __restrict__ ln_in_g, const float* __restrict__ ln_in_b,
                       const float* __restrict__ wq, const float* __restrict__ bq,
                       const float* __restrict__ wk, const float* __restrict__ bk,
                       const float* __restrict__ wv, const float* __restrict__ bv,
                       const float* __restrict__ wi, const float* __restrict__ bi,
                       const float* __restrict__ wf, const float* __restrict__ bf,
                       const float* __restrict__ wo, const float* __restrict__ bo,
                       const float* __restrict__ rd_w1, const float* __restrict__ rd_b1,
                       const float* __restrict__ rd_g, const float* __restrict__ rd_be,
                       const float* __restrict__ rd_w2, const float* __restrict__ rd_b2,
                       float* __restrict__ qo, float* __restrict__ kno, float* __restrict__ vno,
                       float* __restrict__ iko, float* __restrict__ oo,
                       float* __restrict__ knT, float* __restrict__ vnT,
                       float* __restrict__ cg_a, float* __restrict__ fg_a,
                       float* __restrict__ mf_a, float* __restrict__ cks_a,
                       float* __restrict__ qsum_a, float* __restrict__ zc) {
  int bs = blockIdx.x; int b = bs / SS; int s = bs % SS;
  int lane = threadIdx.x;
  __shared__ float xs[FF];
  __shared__ float ks[DD];
  float xv = (lane < FF) ? x[bs * FF + lane] : 0.f;
  float s1x = dsum32(xv);
  float s2x = dsum32(xv * xv);
  if (lane < FF) {
    float mu = s1x * (1.f / FF);
    float var = s2x * (1.f / FF) - mu * mu;
    xs[lane] = (xv - mu) * rsqrtf(var + 1e-5f) * ln_in_g[lane] + ln_in_b[lane];
  }
  __syncthreads();
  int d = lane;
  float aq = bq[d], ak = bk[d], av = bv[d], ao = bo[d], at = rd_b1[d];
#pragma unroll
  for (int f = 0; f < FF; ++f) {
    float xf = xs[f];
    aq = fmaf(xf, wq[d * FF + f], aq);
    ak = fmaf(xf, wk[d * FF + f], ak);
    av = fmaf(xf, wv[d * FF + f], av);
    ao = fmaf(xf, wo[d * FF + f], ao);
    at = fmaf(xf, rd_w1[d * FF + f], at);
  }
  float pit = (lane < FF) ? xs[lane] * wi[lane] : 0.f;
  float pft = (lane < FF) ? xs[lane] * wf[lane] : 0.f;
  float itv = dsum32(pit) + bi[0];
  float ftv = dsum32(pft) + bf[0];
  // regime head: LN(D) -> gelu(exact) -> 4 logits -> softmax[0]
  float s1 = dsum64(at), s2 = dsum64(at * at);
  float mu = s1 * (1.f / DD);
  float var = s2 * (1.f / DD) - mu * mu;
  float tn = (at - mu) * rsqrtf(var + 1e-5f) * rd_g[d] + rd_be[d];
  float ge = 0.5f * tn * (1.f + erff(tn * 0.70710678118654752f));
  float l0 = dsum64(ge * rd_w2[0 * DD + d]) + rd_b2[0];
  float l1 = dsum64(ge * rd_w2[1 * DD + d]) + rd_b2[1];
  float l2 = dsum64(ge * rd_w2[2 * DD + d]) + rd_b2[2];
  float l3 = dsum64(ge * rd_w2[3 * DD + d]) + rd_b2[3];
  float mx = fmaxf(fmaxf(l0, l1), fmaxf(l2, l3));
  float e0 = expf(l0 - mx), e1 = expf(l1 - mx), e2 = expf(l2 - mx), e3 = expf(l3 - mx);
  float mfv = e0 / (e0 + e1 + e2 + e3);
  // normalize k, v
  float kd = ak * 0.125f;
  float kk = dsum64(kd * kd);
  float knd = kd * (8.f / (sqrtf(kk) + 1e-12f));
  float vv = dsum64(av * av);
  float vnd = av * (8.f / (sqrtf(vv) + 1e-6f));
  float ksum = dsum64(knd);
  float qsum = dsum64(aq);
  // stabilized gates
  float mp = fminf(fmaxf(m_prev[b], -100.f), 100.f);
  float mt = fmaxf(ftv, mp + ftv);
  float ig = expf(fminf(fmaxf(itv - mt, -15.f), 15.f));
  float fg = expf(fminf(fmaxf(ftv + mp - mt, -15.f), 15.f));
  float cg = fminf(ig, 1.f);
  qo[bs * DD + d] = aq;
  kno[bs * DD + d] = knd;
  vno[bs * DD + d] = vnd;
  iko[bs * DD + d] = ig * kd;
  oo[bs * DD + d] = 1.f / (1.f + expf(-ao));
  knT[(b * DD + d) * SS + s] = knd;
  vnT[(b * DD + d) * SS + s] = vnd;
  // fused zc = cg * vn^T Cp kn
  ks[d] = knd;
  __syncthreads();
  float acc = 0.f;
  const float* cr = Cp + (b * DD + d) * DD;
#pragma unroll
  for (int j = 0; j < DD; ++j) acc = fmaf(cr[j], ks[j], acc);
  float z = dsum64(vnd * acc);
  if (lane == 0) {
    cg_a[bs] = cg; fg_a[bs] = fg; mf_a[bs] = mfv;
    cks_a[bs] = cg * ksum; qsum_a[bs] = qsum;
    zc[bs] = cg * z;
  }
}

// ---------------- K3: O(S^2) linear-attn p2 + Gram rho ----------------
__global__ void k_main(const float* __restrict__ qo, const float* __restrict__ kno,
                       const float* __restrict__ vno,
                       const float* __restrict__ knT, const float* __restrict__ vnT,
                       const float* __restrict__ cg_a,
                       float* __restrict__ p2, float* __restrict__ rho) {
  int bs = blockIdx.x; int b = bs / SS; int s = bs % SS;
  int lane = threadIdx.x;
  __shared__ float w[64];
  const float* qrow = qo + bs * DD;
  const float* krow = kno + bs * DD;
  const float* vrow = vno + bs * DD;
  float pacc = 0.f, rp = 0.f;
  int sT = s & ~63;
  for (int T = 0; T < sT; T += 64) {
    int t = T + lane;
    float A = 0.f, KK = 0.f, VV = 0.f;
#pragma unroll 8
    for (int j = 0; j < DD; ++j) {
      float kt = knT[(b * DD + j) * SS + t];
      float vt = vnT[(b * DD + j) * SS + t];
      A = fmaf(kt, qrow[j], A);
      KK = fmaf(kt, krow[j], KK);
      VV = fmaf(vt, vrow[j], VV);
    }
    float cgt = cg_a[b * SS + t];
    w[lane] = cgt * A;
    rp = fmaf(2.f * cgt, KK * VV, rp);
    __syncthreads();
#pragma unroll 8
    for (int tl = 0; tl < 64; ++tl)
      pacc = fmaf(w[tl], vno[(b * SS + T + tl) * DD + lane], pacc);
    __syncthreads();
  }
  {
    int T = sT; int t = T + lane;
    float A = 0.f, KK = 0.f, VV = 0.f;
#pragma unroll 8
    for (int j = 0; j < DD; ++j) {
      float kt = knT[(b * DD + j) * SS + t];
      float vt = vnT[(b * DD + j) * SS + t];
      A = fmaf(kt, qrow[j], A);
      KK = fmaf(kt, krow[j], KK);
      VV = fmaf(vt, vrow[j], VV);
    }
    float cgt = cg_a[b * SS + t];
    w[lane] = (t <= s) ? cgt * A : 0.f;
    float wr = (t < s) ? 2.f : (t == s ? 1.f : 0.f);
    rp = fmaf(wr * cgt, KK * VV, rp);
    __syncthreads();
    int tmax = s - sT;
    for (int tl = 0; tl <= tmax; ++tl)
      pacc = fmaf(w[tl], vno[(b * SS + T + tl) * DD + lane], pacc);
  }
  p2[bs * DD + lane] = pacc;
  float rr = dsum64(rp);
  if (lane == 0) rho[bs] = cg_a[bs] * rr;
}

// ------- K4: per-b scalar DPP-scans (fcum, cpd, sn2) + Cp prep + vol norm ----
__global__ void k_scalar_scan(const float* __restrict__ fg_a, const float* __restrict__ zc,
                              const float* __restrict__ rho, const float* __restrict__ Cp,
                              const float* __restrict__ svraw,
                              float* __restrict__ fcum, float* __restrict__ cpd,
                              float* __restrict__ sn2, float* __restrict__ cpr,
                              float* __restrict__ cpn2, float* __restrict__ sv) {
  int b = blockIdx.x; int lane = threadIdx.x;
  float rs = 0.f, r2 = 0.f;
  const float* cr = Cp + (b * DD + lane) * DD;
#pragma unroll
  for (int j = 0; j < DD; ++j) { float c = cr[j]; rs += c; r2 = fmaf(c, c, r2); }
  cpr[b * DD + lane] = rs;
  float tot2 = dsum64(r2);
  if (lane == 0) cpn2[b] = tot2;
  // vol normalize (fused former k_vol_norm)
  float m0 = svraw[b * SS + WVOL - 1];
  float vals[8]; float part = 0.f;
#pragma unroll
  for (int c = 0; c < 8; ++c) {
    int idx = c * 64 + lane;
    float v = (idx < WVOL - 1) ? m0 : svraw[b * SS + idx];
    vals[c] = v; part += v;
  }
  float tot = dsum64(part);
  float inv = 1.f / (tot * (1.f / SS) + 1e-6f);
#pragma unroll
  for (int c = 0; c < 8; ++c) sv[b * SS + c * 64 + lane] = vals[c] * inv;
  // chunked inclusive scans: product(fg), sum(zc), sum(rho)
  float cf = 1.f, cz = 0.f, crr = 0.f;
  for (int c = 0; c < 8; ++c) {
    int bs = b * SS + c * 64 + lane;
    float f = dscan_mul(fg_a[bs]) * cf;
    float z = dscan_add(zc[bs]) + cz;
    float r = dscan_add(rho[bs]) + crr;
    fcum[bs] = f; cpd[bs] = z; sn2[bs] = r;
    cf = rlane(f, 63); cz = rlane(z, 63); crr = rlane(r, 63);
  }
}

// ---------------- K5a/K5b: vector cumsums nacc/racc, 256-block 2-phase -------
__global__ void k_csum(const float* __restrict__ ik, const float* __restrict__ vno,
                       const float* __restrict__ cks_a,
                       float* __restrict__ csn, float* __restrict__ csr) {
  int blk = blockIdx.x; int b = blk / NCH; int w = blk % NCH; int d = threadIdx.x;
  float na = 0.f, ra = 0.f;
#pragma unroll
  for (int t = 0; t < CH; ++t) {
    int bs = b * SS + w * CH + t;
    na += ik[bs * DD + d];
    ra = fmaf(cks_a[bs], vno[bs * DD + d], ra);
  }
  csn[blk * DD + d] = na; csr[blk * DD + d] = ra;
}
__global__ void k_scan_apply(const float* __restrict__ ik, const float* __restrict__ vno,
                             const float* __restrict__ cks_a,
                             const float* __restrict__ csn, const float* __restrict__ csr,
                             float* __restrict__ nacc, float* __restrict__ racc) {
  int blk = blockIdx.x; int b = blk / NCH; int w = blk % NCH; int d = threadIdx.x;
  float na = 0.f, ra = 0.f;
  for (int w2 = 0; w2 < w; ++w2) {
    na += csn[(b * NCH + w2) * DD + d];
    ra += csr[(b * NCH + w2) * DD + d];
  }
#pragma unroll
  for (int t = 0; t < CH; ++t) {
    int bs = b * SS + w * CH + t;
    na += ik[bs * DD + d];
    ra = fmaf(cks_a[bs], vno[bs * DD + d], ra);
    nacc[bs * DD + d] = na;
    racc[bs * DD + d] = ra;
  }
}

// ---------------- K6: SSM scan, one wave per (b, row i); tight chain ---------
__global__ void k_ssm(const float* __restrict__ fcum, const float* __restrict__ racc,
                      const float* __restrict__ cpr, const float* __restrict__ sv,
                      const float* __restrict__ log_lam, const float* __restrict__ log_b,
                      const float* __restrict__ cvec,
                      const float* __restrict__ log_step, const float* __restrict__ vol_gate,
                      const float* __restrict__ ln_g, const float* __restrict__ ln_b,
                      float* __restrict__ ysT) {
  int blk = blockIdx.x; int b = blk >> 6; int i = blk & 63;
  int n = threadIdx.x;
  float st = expf(log_step[0]);
  float lam = -expf(log_lam[n]);
  float ad = (2.f + st * lam) / (2.f - st * lam);
  float bd = st * (1.f + ad) * expf(log_b[n]) * 0.5f;
  float vg = 1.f / (1.f + expf(-vol_gate[n]));
  float g = ln_g[n], be = ln_b[n], cn = cvec[n];
  float cprv = cpr[b * DD + i];
  // preload u/vol into registers: lane t holds step c*64+t
  float u[8], w[8];
#pragma unroll
  for (int c = 0; c < 8; ++c) {
    int s = c * 64 + n; int bs = b * SS + s;
    u[c] = fmaf(fcum[bs], cprv, racc[(size_t)bs * DD + i]) * (1.f / DD);
    w[c] = sv[bs];
  }
  float h = 0.f;
#pragma unroll
  for (int c = 0; c < 8; ++c) {
    float yout = 0.f;
#pragma unroll 4
    for (int t = 0; t < 64; ++t) {
      float uu = rlane(u[c], t);                       // SGPR
      float vv = rlane(w[c], t);                       // SGPR
      float bdu = bd * uu;                             // off-chain
      float rden = __builtin_amdgcn_rcpf(fmaf(vg, vv, 1.f));  // off-chain
      float grden = g * rden, berden = be * rden;      // off-chain
      float ht = fmaf(ad, h, bdu);
      float p1 = ht, p2 = ht * ht;
      p1 += updpp<0x111, 0xF, true>(0.f, p1); p2 += updpp<0x111, 0xF, true>(0.f, p2);
      p1 += updpp<0x112, 0xF, true>(0.f, p1); p2 += updpp<0x112, 0xF, true>(0.f, p2);
      p1 += updpp<0x114, 0xF, true>(0.f, p1); p2 += updpp<0x114, 0xF, true>(0.f, p2);
      p1 += updpp<0x118, 0xF, true>(0.f, p1); p2 += updpp<0x118, 0xF, true>(0.f, p2);
      p1 += updpp<0x142, 0xF, true>(0.f, p1); p2 += updpp<0x142, 0xF, true>(0.f, p2);
      p1 += updpp<0x143, 0xF, true>(0.f, p1); p2 += updpp<0x143, 0xF, true>(0.f, p2);
      float s1 = rlane(p1, 63), s2 = rlane(p2, 63);
      float mu = s1 * (1.f / DD);
      float r2m = fmaf(-mu, s1, s2);                   // s2 - s1*mu = 64*var
      float arg = fmaxf(fmaf(r2m, 1.f / DD, 1e-5f), 1e-5f);
      float irs = __builtin_amdgcn_rsqf(arg);
      float hv = fmaf((ht - mu) * grden, irs, berden); // (ht-mu)*grden || rsq
      h = hv;
      float y = cn * hv;
      y += updpp<0x111, 0xF, true>(0.f, y);
      y += updpp<0x112, 0xF, true>(0.f, y);
      y += updpp<0x114, 0xF, true>(0.f, y);
      y += updpp<0x118, 0xF, true>(0.f, y);
      y += updpp<0x142, 0xF, true>(0.f, y);
      y += updpp<0x143, 0xF, true>(0.f, y);
      float su = rlane(y, 63);                         // SGPR
      yout = (n == t) ? su : yout;                     // cndmask gather
    }
    ysT[(size_t)(b * DD + i) * SS + c * 64 + n] = yout;  // coalesced
  }
}

// ---------------- K7: final readout ----------------
__global__ void k_final(const float* __restrict__ qo, const float* __restrict__ oo,
                        const float* __restrict__ p2, const float* __restrict__ racc,
                        const float* __restrict__ nacc, const float* __restrict__ ysT,
                        const float* __restrict__ Cp, const float* __restrict__ cpr,
                        const float* __restrict__ cpn2,
                        const float* __restrict__ fcum, const float* __restrict__ cpd,
                        const float* __restrict__ sn2,
                        const float* __restrict__ mf_a, const float* __restrict__ qsum_a,
                        const float* __restrict__ n_prev,
                        const float* __restrict__ ssm_log_d, const float* __restrict__ ssm_alpha,
                        const float* __restrict__ ln_mem_g, const float* __restrict__ ln_mem_b,
                        float* __restrict__ out) {
  int bs = blockIdx.x; int b = bs / SS; int s = bs % SS;
  int i = threadIdx.x;
  __shared__ float qv[DD];
  float qi = qo[bs * DD + i];
  qv[i] = qi;
  __syncthreads();
  float P1 = 0.f;
  const float* cr = Cp + (b * DD + i) * DD;
#pragma unroll
  for (int j = 0; j < DD; ++j) P1 = fmaf(cr[j], qv[j], P1);
  float fc = fcum[bs];
  float p = fmaf(fc, P1, p2[bs * DD + i]);
  float r = fmaf(fc, cpr[b * DD + i], racc[bs * DD + i]);
  float R2 = fc * fc * cpn2[b] + 2.f * fc * cpd[bs] + sn2[bs];
  float al = 1.f / (1.f + expf(-ssm_alpha[0]));
  float kap = al + (1.f - al) * expf(ssm_log_d[0]);
  float mfv = mf_a[bs];
  float beta = 1.f + mfv * (kap - 1.f);
  float gam = mfv * (1.f - al);
  float y = ysT[(size_t)(b * DD + i) * SS + s];
  float syr = dsum64(y * r);
  float sy2 = dsum64(y * y);
  float nrm2 = fmaxf(beta * beta * R2 + 2.f * beta * gam * syr + gam * gam * (float)DD * sy2, 0.f);
  float scale = 8.f / (sqrtf(nrm2) + 1e-6f);
  float nt = fmaf(fc, n_prev[b * DD + i], nacc[bs * DD + i]);
  float ndp = dsum64(nt * qi);
  float denom = fmaxf(fabsf(ndp), 1.f);
  float hh = scale * (fmaf(beta, p, gam * y * qsum_a[bs])) / denom;
  float s1 = dsum64(hh), s2 = dsum64(hh * hh);
  float mu = s1 * (1.f / DD);
  float var = fmaxf(s2 * (1.f / DD) - mu * mu, 0.f);
  float o = (hh - mu) * rsqrtf(var + 1e-5f) * ln_mem_g[i] + ln_mem_b[i];
  out[bs * DD + i] = oo[bs * DD + i] * o;
}

extern "C" void kernel_launch(void* const* d_in, const int* in_sizes, int n_in,
                              void* d_out, int out_size, void* d_ws, size_t ws_size,
                              hipStream_t stream) {
  const float* x        = (const float*)d_in[0];
  const float* C_prev   = (const float*)d_in[1];
  const float* n_prev   = (const float*)d_in[2];
  const float* m_prev   = (const float*)d_in[3];
  const float* ln_in_g  = (const float*)d_in[4];
  const float* ln_in_b  = (const float*)d_in[5];
  const float* wq = (const float*)d_in[6];  const float* bq = (const float*)d_in[7];
  const float* wk = (const float*)d_in[8];  const float* bk = (const float*)d_in[9];
  const float* wv = (const float*)d_in[10]; const float* bv = (const float*)d_in[11];
  const float* wi = (const float*)d_in[12]; const float* bi = (const float*)d_in[13];
  const float* wf = (const float*)d_in[14]; const float* bf = (const float*)d_in[15];
  const float* wo = (const float*)d_in[16]; const float* bo = (const float*)d_in[17];
  const float* rd_w1 = (const float*)d_in[18]; const float* rd_b1 = (const float*)d_in[19];
  const float* rd_g  = (const float*)d_in[20]; const float* rd_be = (const float*)d_in[21];
  const float* rd_w2 = (const float*)d_in[22]; const float* rd_b2 = (const float*)d_in[23];
  const float* ssm_log_lam  = (const float*)d_in[24];
  const float* ssm_log_b    = (const float*)d_in[25];
  const float* ssm_c        = (const float*)d_in[26];
  const float* ssm_log_d    = (const float*)d_in[27];
  const float* ssm_log_step = (const float*)d_in[28];
  const float* ssm_vol_gate = (const float*)d_in[29];
  const float* ssm_alpha    = (const float*)d_in[30];
  const float* ssm_ln_g     = (const float*)d_in[31];
  const float* ssm_ln_b     = (const float*)d_in[32];
  const float* ln_mem_g     = (const float*)d_in[33];
  const float* ln_mem_b     = (const float*)d_in[34];
  float* out = (float*)d_out;

  float* W = (float*)d_ws;
  size_t o0 = 0;
  const size_t BS = (size_t)BB * SS, BSD = BS * DD;
  float* sv    = W + o0; o0 += BS;
  float* svraw = W + o0; o0 += BS;
  float* qo   = W + o0; o0 += BSD;
  float* kno  = W + o0; o0 += BSD;
  float* vno  = W + o0; o0 += BSD;
  float* iko  = W + o0; o0 += BSD;
  float* oo   = W + o0; o0 += BSD;
  float* knT  = W + o0; o0 += BSD;
  float* vnT  = W + o0; o0 += BSD;
  float* p2   = W + o0; o0 += BSD;
  float* racc = W + o0; o0 += BSD;
  float* nacc = W + o0; o0 += BSD;
  float* ysT  = W + o0; o0 += BSD;
  float* cg_a = W + o0; o0 += BS;
  float* fg_a = W + o0; o0 += BS;
  float* mf_a = W + o0; o0 += BS;
  float* cks  = W + o0; o0 += BS;
  float* qsum = W + o0; o0 += BS;
  float* zc   = W + o0; o0 += BS;
  float* fcum = W + o0; o0 += BS;
  float* cpd  = W + o0; o0 += BS;
  float* rho  = W + o0; o0 += BS;
  float* sn2  = W + o0; o0 += BS;
  float* cpr  = W + o0; o0 += (size_t)BB * DD;
  float* cpn2 = W + o0; o0 += BB;
  float* csn  = W + o0; o0 += (size_t)BB * NCH * DD;
  float* csr  = W + o0; o0 += (size_t)BB * NCH * DD;

  hipLaunchKernelGGL(k_vol_std, dim3(BB, SS - WVOL + 1), dim3(64), 0, stream, x, svraw);
  hipLaunchKernelGGL(k_proj, dim3(BB * SS), dim3(64), 0, stream,
                     x, m_prev, C_prev, ln_in_g, ln_in_b, wq, bq, wk, bk, wv, bv, wi, bi,
                     wf, bf, wo, bo, rd_w1, rd_b1, rd_g, rd_be, rd_w2, rd_b2,
                     qo, kno, vno, iko, oo, knT, vnT, cg_a, fg_a, mf_a, cks, qsum, zc);
  hipLaunchKernelGGL(k_main, dim3(BB * SS), dim3(64), 0, stream,
                     qo, kno, vno, knT, vnT, cg_a, p2, rho);
  hipLaunchKernelGGL(k_scalar_scan, dim3(BB), dim3(64), 0, stream,
                     fg_a, zc, rho, C_prev, svraw, fcum, cpd, sn2, cpr, cpn2, sv);
  hipLaunchKernelGGL(k_csum, dim3(BB * NCH), dim3(64), 0, stream,
                     iko, vno, cks, csn, csr);
  hipLaunchKernelGGL(k_scan_apply, dim3(BB * NCH), dim3(64), 0, stream,
                     iko, vno, cks, csn, csr, nacc, racc);
  hipLaunchKernelGGL(k_ssm, dim3(BB * DD), dim3(64), 0, stream,
                     fcum, racc, cpr, sv, ssm_log_lam, ssm_log_b, ssm_c,
                     ssm_log_step, ssm_vol_gate, ssm_ln_g, ssm_ln_b, ysT);
  hipLaunchKernelGGL(k_final, dim3(BB * SS), dim3(64), 0, stream,
                     qo, oo, p2, racc, nacc, ysT, C_prev, cpr, cpn2, fcum, cpd, sn2,
                     mf_a, qsum, n_prev, ssm_log_d, ssm_alpha, ln_mem_g, ln_mem_b, out);
}